// Round 11
// baseline (498.543 us; speedup 1.0000x reference)
//
#include <hip/hip_runtime.h>
#include <hip/hip_bf16.h>

// B=128, N=256, D=H=256. out = [weighted (B*N*D), attention (B*N*N)] fp32.
// Round-10 structure with the r8-vs-r10 A/B cherry-picked:
//   proj_qkv: r8 version (NO prefetch — L2-hot operands; prefetch cost +7 µs
//     via barrier-drain + register pressure).
//   scores_st: r10 version (WITH prefetch — q/k are 8.4 MB/XCD > L2, HBM-latency
//     bound; early issue gained ~8-10 µs).
// Chain: 1024-block sq_bf; final: smode-2 gemm_mfma; rho via rho_finalize.

#define NB 128
#define MAT 65536
#define BIG 8388608LL

typedef __attribute__((ext_vector_type(4))) float floatx4;
typedef __attribute__((ext_vector_type(4))) float f4v;
typedef __attribute__((ext_vector_type(8))) short short8v;
typedef __attribute__((ext_vector_type(4))) short short4v;

__device__ __forceinline__ short f2bf(float x) {
  union { float f; unsigned u; } v; v.f = x;
  unsigned r = v.u + 0x7fff + ((v.u >> 16) & 1);
  return (short)(r >> 16);
}
__device__ __forceinline__ float bf2f(short h) {
  union { unsigned u; float f; } v; v.u = ((unsigned)(unsigned short)h) << 16; return v.f;
}

// ---------------- generic split-bf16 GEMM (FINAL GEMM only) ------------------------
template<bool TB, bool BATCHED>
__global__ __launch_bounds__(256) void gemm_mfma(
    const float* __restrict__ A, const float* __restrict__ B, float* __restrict__ C,
    long long sA, long long sB, long long sC,
    const float* __restrict__ bias,
    const float* __restrict__ scale_ptr, int sstride, int smode,
    float* __restrict__ norm_out,
    float* __restrict__ att_out,
    const float* __restrict__ B2, const float* __restrict__ bias2, float* __restrict__ C2,
    const float* __restrict__ B3, float* __restrict__ C3,
    const float* __restrict__ bsc, const float* __restrict__ bsb)
{
  __shared__ short sAhi[128 * 32], sAlo[128 * 32];
  __shared__ short sBhi[128 * 40], sBlo[128 * 40];

  int bz, m0, n0;
  if constexpr (BATCHED) {
    int lin = blockIdx.x;
    int xcd = lin & 7;
    int s = lin >> 3;
    bz = xcd * 16 + (s >> 2);
    int tile = s & 3;
    m0 = (tile >> 1) * 128;
    n0 = (tile & 1) * 128;
  } else {
    bz = 0;
    m0 = blockIdx.y * 128;
    n0 = (blockIdx.x & 1) * 128;
    int sel = blockIdx.x >> 1;
    if (sel == 1) { B = B2; bias = bias2; C = C2; }
    else if (sel == 2) { B = B3; bias = nullptr; C = C3; }
  }
  A += (long long)bz * sA;
  B += (long long)bz * sB;
  C += (long long)bz * sC;

  const int t = threadIdx.x;
  const int lane = t & 63;
  const int wave = t >> 6;
  const int wm = wave >> 1, wn = wave & 1;
  const int q = lane >> 4, c16 = lane & 15;

  float alpha = 1.0f;
  if (smode == 1) alpha = 1.0f / scale_ptr[bz * sstride];
  else if (smode == 2) alpha = scale_ptr[bz * sstride];

  float rinv_att = alpha;
  const bool do_att = (att_out != nullptr) && (n0 == 0);

  float binv = 1.0f;
  if (bsc) binv = 1.0f / bsc[0];

  floatx4 acc[4][4];
  #pragma unroll
  for (int i = 0; i < 4; i++)
    #pragma unroll
    for (int j = 0; j < 4; j++)
      acc[i][j] = (floatx4){0.f, 0.f, 0.f, 0.f};

  for (int k0 = 0; k0 < 256; k0 += 32) {
    #pragma unroll
    for (int i = 0; i < 4; i++) {
      int f = t + i * 256;
      int row = f >> 3, c4 = f & 7;
      f4v v = *(const f4v*)(A + (long long)(m0 + row) * 256 + k0 + c4 * 4);
      if (do_att)
        *(f4v*)(att_out + (long long)bz * MAT + (long long)(m0 + row) * 256 + k0 + c4 * 4)
            = v * rinv_att;
      short4v h, l;
      #pragma unroll
      for (int e = 0; e < 4; e++) {
        short hh = f2bf(v[e]);
        h[e] = hh;
        l[e] = f2bf(v[e] - bf2f(hh));
      }
      *(short4v*)&sAhi[row * 32 + c4 * 4] = h;
      *(short4v*)&sAlo[row * 32 + c4 * 4] = l;
    }
    if constexpr (TB) {
      #pragma unroll
      for (int i = 0; i < 4; i++) {
        int f = t + i * 256;
        int row = f >> 3, c4 = f & 7;
        f4v v = *(const f4v*)(B + (long long)(n0 + row) * 256 + k0 + c4 * 4);
        short4v h, l;
        #pragma unroll
        for (int e = 0; e < 4; e++) {
          short hh = f2bf(v[e]);
          h[e] = hh;
          l[e] = f2bf(v[e] - bf2f(hh));
        }
        *(short4v*)&sBhi[row * 40 + c4 * 4] = h;
        *(short4v*)&sBlo[row * 40 + c4 * 4] = l;
      }
      __syncthreads();
    } else {
      __shared__ float sT[32 * 132];
      #pragma unroll
      for (int i = 0; i < 4; i++) {
        int f = t + i * 256;
        int kk = f >> 5, n4 = f & 31;
        f4v v = *(const f4v*)(B + (long long)(k0 + kk) * 256 + n0 + n4 * 4);
        if (bsb) {
          #pragma unroll
          for (int e = 0; e < 4; e++) v[e] = v[e] * binv + bsb[n0 + n4 * 4 + e];
        }
        *(f4v*)&sT[kk * 132 + n4 * 4] = v;
      }
      __syncthreads();
      int n = t & 127, kh = t >> 7;
      short8v h0, h1, l0, l1;
      #pragma unroll
      for (int j = 0; j < 8; j++) {
        float x0 = sT[(kh * 16 + j) * 132 + n];
        float x1 = sT[(kh * 16 + 8 + j) * 132 + n];
        short a0 = f2bf(x0), a1 = f2bf(x1);
        h0[j] = a0; l0[j] = f2bf(x0 - bf2f(a0));
        h1[j] = a1; l1[j] = f2bf(x1 - bf2f(a1));
      }
      *(short8v*)&sBhi[n * 40 + kh * 16] = h0;
      *(short8v*)&sBhi[n * 40 + kh * 16 + 8] = h1;
      *(short8v*)&sBlo[n * 40 + kh * 16] = l0;
      *(short8v*)&sBlo[n * 40 + kh * 16 + 8] = l1;
      __syncthreads();
    }

    short8v ah[4], al[4], bh[4], bl[4];
    #pragma unroll
    for (int fi = 0; fi < 4; fi++) {
      int r = wm * 64 + fi * 16 + c16;
      ah[fi] = *(short8v*)&sAhi[r * 32 + q * 8];
      al[fi] = *(short8v*)&sAlo[r * 32 + q * 8];
    }
    #pragma unroll
    for (int fj = 0; fj < 4; fj++) {
      int r = wn * 64 + fj * 16 + c16;
      bh[fj] = *(short8v*)&sBhi[r * 40 + q * 8];
      bl[fj] = *(short8v*)&sBlo[r * 40 + q * 8];
    }
    #pragma unroll
    for (int fi = 0; fi < 4; fi++)
      #pragma unroll
      for (int fj = 0; fj < 4; fj++) {
        acc[fi][fj] = __builtin_amdgcn_mfma_f32_16x16x32_bf16(al[fi], bh[fj], acc[fi][fj], 0, 0, 0);
        acc[fi][fj] = __builtin_amdgcn_mfma_f32_16x16x32_bf16(ah[fi], bl[fj], acc[fi][fj], 0, 0, 0);
        acc[fi][fj] = __builtin_amdgcn_mfma_f32_16x16x32_bf16(ah[fi], bh[fj], acc[fi][fj], 0, 0, 0);
      }
    __syncthreads();
  }

  float ssq = 0.f;
  #pragma unroll
  for (int fi = 0; fi < 4; fi++) {
    #pragma unroll
    for (int fj = 0; fj < 4; fj++) {
      int col = n0 + wn * 64 + fj * 16 + c16;
      float bb = bias ? bias[col] : 0.f;
      #pragma unroll
      for (int r = 0; r < 4; r++) {
        int row = m0 + wm * 64 + fi * 16 + q * 4 + r;
        float v = acc[fi][fj][r] * alpha + bb;
        C[(long long)row * 256 + col] = v;
        ssq += v * v;
      }
    }
  }

  if (norm_out) {
    float* red = (float*)sAhi;
    red[t] = ssq;
    __syncthreads();
    for (int off = 128; off > 0; off >>= 1) {
      if (t < off) red[t] += red[t + off];
      __syncthreads();
    }
    if (t == 0) {
      int tl = ((m0 >> 7) << 1) | (n0 >> 7);
      norm_out[bz * 4 + tl] = red[0];
    }
  }
}

// ---------------- split inputs: Wq/Wk/Wv and x -> bf16 hi/lo -----------------------
__global__ __launch_bounds__(256) void split_inputs(
    const float* __restrict__ Wq, const float* __restrict__ Wk,
    const float* __restrict__ Wv, short* __restrict__ ws6,
    const float* __restrict__ x, short* __restrict__ xhi, short* __restrict__ xlo)
{
  int b = blockIdx.x;
  int t = threadIdx.x;
  if (b < 192) {
    int gid = b * 256 + t;
    int m = gid >> 14;                          // 0..2
    int off = (gid & 16383) * 4;
    const float* src = (m == 0) ? Wq : (m == 1) ? Wk : Wv;
    f4v v = *(const f4v*)(src + off);
    short4v h, l;
    #pragma unroll
    for (int e = 0; e < 4; e++) {
      short hh = f2bf(v[e]);
      h[e] = hh;
      l[e] = f2bf(v[e] - bf2f(hh));
    }
    *(short4v*)&ws6[(long long)(m * 2) * MAT + off] = h;
    *(short4v*)&ws6[(long long)(m * 2 + 1) * MAT + off] = l;
  } else {
    long long off = ((long long)(b - 192) * 256 + t) * 8;
    #pragma unroll
    for (int half = 0; half < 2; half++) {
      f4v v = *(const f4v*)(x + off + half * 4);
      short4v h, l;
      #pragma unroll
      for (int e = 0; e < 4; e++) {
        short hh = f2bf(v[e]);
        h[e] = hh;
        l[e] = f2bf(v[e] - bf2f(hh));
      }
      *(short4v*)&xhi[off + half * 4] = h;
      *(short4v*)&xlo[off + half * 4] = l;
    }
  }
}

// ---------------- projections: XCD-grouped, copy-staged A AND B (r8, NO prefetch) --
// 1536 blocks: xcd = lin&7, idx = lin>>3; m_tile = xcd*32 + idx/6; role idx%6.
// L2-hot operands — r10 A/B showed register prefetch COSTS ~7 µs here.
__global__ __launch_bounds__(256) void proj_qkv(
    const short* __restrict__ xhi, const short* __restrict__ xlo,
    const short* __restrict__ wsp,
    const float* __restrict__ bq, const float* __restrict__ bk,
    short* __restrict__ qhi, short* __restrict__ qlo,
    short* __restrict__ khi, short* __restrict__ klo,
    float* __restrict__ vals)
{
  __shared__ short sAhi[128 * 32], sAlo[128 * 32];
  __shared__ short sBhi[128 * 40], sBlo[128 * 40];

  const int lin = blockIdx.x;
  const int xcd = lin & 7;
  const int idx = lin >> 3;
  const int mloc = idx / 6;
  const int s6 = idx - mloc * 6;
  const int m0 = (xcd * 32 + mloc) * 128;
  const int sel = s6 >> 1;
  const int n0 = (s6 & 1) * 128;

  const short* wb_hi = wsp + (long long)(sel * 2) * MAT;
  const short* wb_lo = wsp + (long long)(sel * 2 + 1) * MAT;

  const int t = threadIdx.x;
  const int lane = t & 63;
  const int wave = t >> 6;
  const int wm = wave >> 1, wn = wave & 1;
  const int q = lane >> 4, c16 = lane & 15;

  floatx4 acc[4][4];
  #pragma unroll
  for (int i = 0; i < 4; i++)
    #pragma unroll
    for (int j = 0; j < 4; j++)
      acc[i][j] = (floatx4){0.f, 0.f, 0.f, 0.f};

  for (int k0 = 0; k0 < 256; k0 += 32) {
    #pragma unroll
    for (int i = 0; i < 2; i++) {
      int chunk = t + i * 256;                 // 0..511
      int row = chunk >> 2, c8 = chunk & 3;
      long long ga = (long long)(m0 + row) * 256 + k0 + c8 * 8;
      *(short8v*)&sAhi[row * 32 + c8 * 8] = *(const short8v*)(xhi + ga);
      *(short8v*)&sAlo[row * 32 + c8 * 8] = *(const short8v*)(xlo + ga);
    }
    #pragma unroll
    for (int i = 0; i < 2; i++) {
      int chunk = t + i * 256;
      int row = chunk >> 2, c8 = chunk & 3;
      long long gr = (long long)(n0 + row) * 256 + k0 + c8 * 8;
      *(short8v*)&sBhi[row * 40 + c8 * 8] = *(const short8v*)(wb_hi + gr);
      *(short8v*)&sBlo[row * 40 + c8 * 8] = *(const short8v*)(wb_lo + gr);
    }
    __syncthreads();

    short8v ah[4], al[4], bh[4], bl[4];
    #pragma unroll
    for (int fi = 0; fi < 4; fi++) {
      int r = wm * 64 + fi * 16 + c16;
      ah[fi] = *(short8v*)&sAhi[r * 32 + q * 8];
      al[fi] = *(short8v*)&sAlo[r * 32 + q * 8];
    }
    #pragma unroll
    for (int fj = 0; fj < 4; fj++) {
      int r = wn * 64 + fj * 16 + c16;
      bh[fj] = *(short8v*)&sBhi[r * 40 + q * 8];
      bl[fj] = *(short8v*)&sBlo[r * 40 + q * 8];
    }
    #pragma unroll
    for (int fi = 0; fi < 4; fi++)
      #pragma unroll
      for (int fj = 0; fj < 4; fj++) {
        acc[fi][fj] = __builtin_amdgcn_mfma_f32_16x16x32_bf16(al[fi], bh[fj], acc[fi][fj], 0, 0, 0);
        acc[fi][fj] = __builtin_amdgcn_mfma_f32_16x16x32_bf16(ah[fi], bl[fj], acc[fi][fj], 0, 0, 0);
        acc[fi][fj] = __builtin_amdgcn_mfma_f32_16x16x32_bf16(ah[fi], bh[fj], acc[fi][fj], 0, 0, 0);
      }
    __syncthreads();
  }

  if (sel < 2) {
    short* ohi = sel ? khi : qhi;
    short* olo = sel ? klo : qlo;
    const float* bb = sel ? bk : bq;
    #pragma unroll
    for (int fi = 0; fi < 4; fi++)
      #pragma unroll
      for (int fj = 0; fj < 4; fj++) {
        int col = n0 + wn * 64 + fj * 16 + c16;
        float b = bb[col];
        #pragma unroll
        for (int r = 0; r < 4; r++) {
          long long row = m0 + wm * 64 + fi * 16 + q * 4 + r;
          float v = acc[fi][fj][r] + b;
          short h = f2bf(v);
          ohi[row * 256 + col] = h;
          olo[row * 256 + col] = f2bf(v - bf2f(h));
        }
      }
  } else {
    #pragma unroll
    for (int fi = 0; fi < 4; fi++)
      #pragma unroll
      for (int fj = 0; fj < 4; fj++) {
        int col = n0 + wn * 64 + fj * 16 + c16;
        #pragma unroll
        for (int r = 0; r < 4; r++) {
          long long row = m0 + wm * 64 + fi * 16 + q * 4 + r;
          vals[row * 256 + col] = acc[fi][fj][r];
        }
      }
  }
}

// ---------------- scores = q @ k^T: copy-staged + register prefetch (r10) ----------
// q/k splits are 8.4 MB/XCD (> 4 MB L2) -> HBM-latency bound; prefetch helps here.
// norm slot 8-wide: writes bz*8+tile, zeros 4..7.
__global__ __launch_bounds__(256) void scores_st(
    const short* __restrict__ qhi, const short* __restrict__ qlo,
    const short* __restrict__ khi, const short* __restrict__ klo,
    float* __restrict__ S, float* __restrict__ norm_out)
{
  __shared__ short sAhi[128 * 32], sAlo[128 * 32];
  __shared__ short sBhi[128 * 40], sBlo[128 * 40];
  __shared__ float red[256];

  const int lin = blockIdx.x;
  const int xcd = lin & 7, s = lin >> 3;
  const int bz = xcd * 16 + (s >> 2);
  const int tile = s & 3;
  const int m0 = (tile >> 1) * 128, n0 = (tile & 1) * 128;

  const int t = threadIdx.x;
  const int lane = t & 63;
  const int wave = t >> 6;
  const int wm = wave >> 1, wn = wave & 1;
  const int q = lane >> 4, c16 = lane & 15;
  const int srow = t >> 2, sc8 = (t & 3) * 8;

  floatx4 acc[4][4];
  #pragma unroll
  for (int i = 0; i < 4; i++)
    #pragma unroll
    for (int j = 0; j < 4; j++)
      acc[i][j] = (floatx4){0.f, 0.f, 0.f, 0.f};

  const long long abase = (long long)(bz * 256 + m0) * 256;
  const long long bbase = (long long)(bz * 256 + n0) * 256;

  short8v pAh[2], pAl[2], pBh[2], pBl[2];
  {
    #pragma unroll
    for (int i = 0; i < 2; i++) {
      long long ga = abase + (long long)(srow + i * 64) * 256 + sc8;
      long long gb = bbase + (long long)(srow + i * 64) * 256 + sc8;
      pAh[i] = *(const short8v*)(qhi + ga);
      pAl[i] = *(const short8v*)(qlo + ga);
      pBh[i] = *(const short8v*)(khi + gb);
      pBl[i] = *(const short8v*)(klo + gb);
    }
  }

  for (int k0 = 0; k0 < 256; k0 += 32) {
    #pragma unroll
    for (int i = 0; i < 2; i++) {
      int row = srow + i * 64;
      *(short8v*)&sAhi[row * 32 + sc8] = pAh[i];
      *(short8v*)&sAlo[row * 32 + sc8] = pAl[i];
      *(short8v*)&sBhi[row * 40 + sc8] = pBh[i];
      *(short8v*)&sBlo[row * 40 + sc8] = pBl[i];
    }
    __syncthreads();

    if (k0 < 224) {
      int kn = k0 + 32;
      #pragma unroll
      for (int i = 0; i < 2; i++) {
        long long ga = abase + (long long)(srow + i * 64) * 256 + kn + sc8;
        long long gb = bbase + (long long)(srow + i * 64) * 256 + kn + sc8;
        pAh[i] = *(const short8v*)(qhi + ga);
        pAl[i] = *(const short8v*)(qlo + ga);
        pBh[i] = *(const short8v*)(khi + gb);
        pBl[i] = *(const short8v*)(klo + gb);
      }
    }

    short8v ah[4], al[4], bh[4], bl[4];
    #pragma unroll
    for (int fi = 0; fi < 4; fi++) {
      int r = wm * 64 + fi * 16 + c16;
      ah[fi] = *(short8v*)&sAhi[r * 32 + q * 8];
      al[fi] = *(short8v*)&sAlo[r * 32 + q * 8];
    }
    #pragma unroll
    for (int fj = 0; fj < 4; fj++) {
      int r = wn * 64 + fj * 16 + c16;
      bh[fj] = *(short8v*)&sBhi[r * 40 + q * 8];
      bl[fj] = *(short8v*)&sBlo[r * 40 + q * 8];
    }
    #pragma unroll
    for (int fi = 0; fi < 4; fi++)
      #pragma unroll
      for (int fj = 0; fj < 4; fj++) {
        acc[fi][fj] = __builtin_amdgcn_mfma_f32_16x16x32_bf16(al[fi], bh[fj], acc[fi][fj], 0, 0, 0);
        acc[fi][fj] = __builtin_amdgcn_mfma_f32_16x16x32_bf16(ah[fi], bl[fj], acc[fi][fj], 0, 0, 0);
        acc[fi][fj] = __builtin_amdgcn_mfma_f32_16x16x32_bf16(ah[fi], bh[fj], acc[fi][fj], 0, 0, 0);
      }
    __syncthreads();
  }

  float* C = S + (long long)bz * MAT;
  float ssq = 0.f;
  #pragma unroll
  for (int fi = 0; fi < 4; fi++)
    #pragma unroll
    for (int fj = 0; fj < 4; fj++) {
      int col = n0 + wn * 64 + fj * 16 + c16;
      #pragma unroll
      for (int r = 0; r < 4; r++) {
        int row = m0 + wm * 64 + fi * 16 + q * 4 + r;
        float v = acc[fi][fj][r];
        C[(long long)row * 256 + col] = v;
        ssq += v * v;
      }
    }

  red[t] = ssq;
  __syncthreads();
  for (int o = 128; o > 0; o >>= 1) {
    if (t < o) red[t] += red[t + o];
    __syncthreads();
  }
  if (t == 0) norm_out[bz * 8 + tile] = red[0];
  if (t == 1) norm_out[bz * 8 + 4 + tile] = 0.f;
}

// ---------------- chain epilogue (sq_f32bf): alpha*acc -> bf16 tile + norm ---------
__device__ __forceinline__ void chain_epilogue(
    short* LB, float* red, floatx4 (&acc)[4][4], float alpha,
    int m0, int n0, int wm, int wn, int q, int c16, int t,
    short* __restrict__ Mout,
    float* __restrict__ nout, int nidx, bool write_out)
{
  __syncthreads();
  float ssq = 0.f;
  #pragma unroll
  for (int fi = 0; fi < 4; fi++)
    #pragma unroll
    for (int fj = 0; fj < 4; fj++) {
      int lcol = wn * 64 + fj * 16 + c16;
      #pragma unroll
      for (int r = 0; r < 4; r++) {
        int lrow = wm * 64 + fi * 16 + q * 4 + r;
        float v = acc[fi][fj][r] * alpha;
        ssq += v * v;
        if (write_out) LB[lrow * 128 + lcol] = f2bf(v);
      }
    }

  if (write_out) {
    __syncthreads();
    int lr = t >> 1, off = (t & 1) * 64;
    #pragma unroll
    for (int jc = 0; jc < 8; jc++)
      *(short8v*)(Mout + (long long)(m0 + lr) * 256 + n0 + off + jc * 8)
          = *(const short8v*)&LB[lr * 128 + off + jc * 8];
  }

  red[t] = ssq;
  __syncthreads();
  for (int off2 = 128; off2 > 0; off2 >>= 1) {
    if (t < off2) red[t] += red[t + off2];
    __syncthreads();
  }
  if (t == 0) nout[nidx] = red[0];
}

// ---------------- squaring 1: fp32 S (split 3-MFMA) -> bf16 M ----------------------
// norm slot 8-wide (writes bz*8+tile, zeros 4..7).
__global__ __launch_bounds__(256) void sq_f32bf(
    const float* __restrict__ S, short* __restrict__ Mo,
    const float* __restrict__ nprev, float* __restrict__ nout)
{
  __shared__ short SM[18432];
  __shared__ float sT[32 * 132];
  __shared__ float red[256];
  short* sAhi = SM;
  short* sAlo = SM + 4096;
  short* sBhi = SM + 8192;
  short* sBlo = SM + 13312;

  int lin = blockIdx.x;
  int xcd = lin & 7, s = lin >> 3;
  int bz = xcd * 16 + (s >> 2);
  int tile = s & 3;
  int m0 = (tile >> 1) * 128, n0 = (tile & 1) * 128;
  const float* A = S + (long long)bz * MAT;

  const int t = threadIdx.x;
  const int lane = t & 63;
  const int wave = t >> 6;
  const int wm = wave >> 1, wn = wave & 1;
  const int q = lane >> 4, c16 = lane & 15;

  floatx4 acc[4][4];
  #pragma unroll
  for (int i = 0; i < 4; i++)
    #pragma unroll
    for (int j = 0; j < 4; j++)
      acc[i][j] = (floatx4){0.f, 0.f, 0.f, 0.f};

  for (int k0 = 0; k0 < 256; k0 += 32) {
    #pragma unroll
    for (int i = 0; i < 4; i++) {
      int f = t + i * 256;
      int row = f >> 3, c4 = f & 7;
      f4v v = *(const f4v*)(A + (long long)(m0 + row) * 256 + k0 + c4 * 4);
      short4v h, l;
      #pragma unroll
      for (int e = 0; e < 4; e++) {
        short hh = f2bf(v[e]);
        h[e] = hh;
        l[e] = f2bf(v[e] - bf2f(hh));
      }
      *(short4v*)&sAhi[row * 32 + c4 * 4] = h;
      *(short4v*)&sAlo[row * 32 + c4 * 4] = l;
    }
    #pragma unroll
    for (int i = 0; i < 4; i++) {
      int f = t + i * 256;
      int kk = f >> 5, n4 = f & 31;
      f4v v = *(const f4v*)(A + (long long)(k0 + kk) * 256 + n0 + n4 * 4);
      *(f4v*)&sT[kk * 132 + n4 * 4] = v;
    }
    __syncthreads();
    {
      int n = t & 127, kh = t >> 7;
      short8v h0, h1, l0, l1;
      #pragma unroll
      for (int j = 0; j < 8; j++) {
        float x0 = sT[(kh * 16 + j) * 132 + n];
        float x1 = sT[(kh * 16 + 8 + j) * 132 + n];
        short a0 = f2bf(x0), a1 = f2bf(x1);
        h0[j] = a0; l0[j] = f2bf(x0 - bf2f(a0));
        h1[j] = a1; l1[j] = f2bf(x1 - bf2f(a1));
      }
      *(short8v*)&sBhi[n * 40 + kh * 16] = h0;
      *(short8v*)&sBhi[n * 40 + kh * 16 + 8] = h1;
      *(short8v*)&sBlo[n * 40 + kh * 16] = l0;
      *(short8v*)&sBlo[n * 40 + kh * 16 + 8] = l1;
    }
    __syncthreads();

    short8v ah[4], al[4], bh[4], bl[4];
    #pragma unroll
    for (int fi = 0; fi < 4; fi++) {
      int r = wm * 64 + fi * 16 + c16;
      ah[fi] = *(short8v*)&sAhi[r * 32 + q * 8];
      al[fi] = *(short8v*)&sAlo[r * 32 + q * 8];
    }
    #pragma unroll
    for (int fj = 0; fj < 4; fj++) {
      int r = wn * 64 + fj * 16 + c16;
      bh[fj] = *(short8v*)&sBhi[r * 40 + q * 8];
      bl[fj] = *(short8v*)&sBlo[r * 40 + q * 8];
    }
    #pragma unroll
    for (int fi = 0; fi < 4; fi++)
      #pragma unroll
      for (int fj = 0; fj < 4; fj++) {
        acc[fi][fj] = __builtin_amdgcn_mfma_f32_16x16x32_bf16(al[fi], bh[fj], acc[fi][fj], 0, 0, 0);
        acc[fi][fj] = __builtin_amdgcn_mfma_f32_16x16x32_bf16(ah[fi], bl[fj], acc[fi][fj], 0, 0, 0);
        acc[fi][fj] = __builtin_amdgcn_mfma_f32_16x16x32_bf16(ah[fi], bh[fj], acc[fi][fj], 0, 0, 0);
      }
    __syncthreads();
  }

  const float* p = nprev + bz * 8;
  float alpha = 1.0f / (p[0] + p[1] + p[2] + p[3]);
  chain_epilogue(SM, red, acc, alpha, m0, n0, wm, wn, q, c16, t,
                 Mo + (long long)bz * MAT, nout, bz * 8 + tile, true);
  if (t == 1) nout[bz * 8 + 4 + tile] = 0.f;
}

// ---------------- squarings 2..12: 1024 blocks, 64x128 tiles, dbuf + prefetch ------
template<bool WRITE_OUT>
__global__ __launch_bounds__(256) void sq_bf(
    const short* __restrict__ Mi, short* __restrict__ Mo,
    const float* __restrict__ nprev, float* __restrict__ nout)
{
  __shared__ short SMEM[9216];    // Bs dbuf = 2 x [128][36]; epilogue LB 64x128 fits
  __shared__ float red[4];
  short* BsA = SMEM;
  short* BsB = SMEM + 4608;

  int lin = blockIdx.x;
  int xcd = lin & 7, s = lin >> 3;     // s 0..127
  int bz = xcd * 16 + (s >> 3);
  int tile = s & 7;
  int m0 = (tile >> 1) * 64, n0 = (tile & 1) * 128;

  const short* A = Mi + (long long)bz * MAT;

  const int t = threadIdx.x;
  const int lane = t & 63;
  const int wave = t >> 6;
  const int wm = wave >> 1, wn = wave & 1;   // wave tile 32x64
  const int q = lane >> 4, c16 = lane & 15;
  const int g = t >> 5, cc = t & 31;   // staging: 8 k-groups x 32 col-chunks

  floatx4 acc[2][4];
  #pragma unroll
  for (int i = 0; i < 2; i++)
    #pragma unroll
    for (int j = 0; j < 4; j++)
      acc[i][j] = (floatx4){0.f, 0.f, 0.f, 0.f};

  short4v r0 = *(const short4v*)(A + (long long)(g * 4 + 0) * 256 + n0 + cc * 4);
  short4v r1 = *(const short4v*)(A + (long long)(g * 4 + 1) * 256 + n0 + cc * 4);
  short4v r2 = *(const short4v*)(A + (long long)(g * 4 + 2) * 256 + n0 + cc * 4);
  short4v r3 = *(const short4v*)(A + (long long)(g * 4 + 3) * 256 + n0 + cc * 4);

  for (int k0 = 0; k0 < 256; k0 += 32) {
    short* Bw = ((k0 >> 5) & 1) ? BsB : BsA;
    #pragma unroll
    for (int j = 0; j < 4; j++) {
      short4v w4 = (short4v){r0[j], r1[j], r2[j], r3[j]};
      *(short4v*)&Bw[(cc * 4 + j) * 36 + g * 4] = w4;
    }
    __syncthreads();

    if (k0 < 224) {
      int kn = k0 + 32;
      r0 = *(const short4v*)(A + (long long)(kn + g * 4 + 0) * 256 + n0 + cc * 4);
      r1 = *(const short4v*)(A + (long long)(kn + g * 4 + 1) * 256 + n0 + cc * 4);
      r2 = *(const short4v*)(A + (long long)(kn + g * 4 + 2) * 256 + n0 + cc * 4);
      r3 = *(const short4v*)(A + (long long)(kn + g * 4 + 3) * 256 + n0 + cc * 4);
    }

    short8v a[2], b[4];
    #pragma unroll
    for (int fi = 0; fi < 2; fi++)
      a[fi] = *(const short8v*)(A + (long long)(m0 + wm * 32 + fi * 16 + c16) * 256 + k0 + q * 8);
    #pragma unroll
    for (int fj = 0; fj < 4; fj++) {
      int n = wn * 64 + fj * 16 + c16;
      short4v lo = *(const short4v*)&Bw[n * 36 + q * 8];
      short4v hi = *(const short4v*)&Bw[n * 36 + q * 8 + 4];
      b[fj] = __builtin_shufflevector(lo, hi, 0, 1, 2, 3, 4, 5, 6, 7);
    }
    #pragma unroll
    for (int fi = 0; fi < 2; fi++)
      #pragma unroll
      for (int fj = 0; fj < 4; fj++)
        acc[fi][fj] = __builtin_amdgcn_mfma_f32_16x16x32_bf16(a[fi], b[fj], acc[fi][fj], 0, 0, 0);
  }

  const float* p = nprev + bz * 8;
  float alpha = 1.0f / (p[0] + p[1] + p[2] + p[3] + p[4] + p[5] + p[6] + p[7]);

  __syncthreads();   // all Bw reads of the k-loop consumed before LB reuse
  short* LB = SMEM;
  float ssq = 0.f;
  #pragma unroll
  for (int fi = 0; fi < 2; fi++)
    #pragma unroll
    for (int fj = 0; fj < 4; fj++) {
      int lcol = wn * 64 + fj * 16 + c16;
      #pragma unroll
      for (int r = 0; r < 4; r++) {
        int lrow = wm * 32 + fi * 16 + q * 4 + r;
        float v = acc[fi][fj][r] * alpha;
        ssq += v * v;
        if (WRITE_OUT) LB[lrow * 128 + lcol] = f2bf(v);
      }
    }

  if (WRITE_OUT) {
    __syncthreads();
    int lr = t >> 2, off = (t & 3) * 32;
    #pragma unroll
    for (int jc = 0; jc < 4; jc++)
      *(short8v*)(Mo + (long long)bz * MAT + (long long)(m0 + lr) * 256 + n0 + off + jc * 8)
          = *(const short8v*)&LB[lr * 128 + off + jc * 8];
  }

  #pragma unroll
  for (int off2 = 32; off2 > 0; off2 >>= 1)
    ssq += __shfl_xor(ssq, off2, 64);
  if (lane == 0) red[wave] = ssq;
  __syncthreads();
  if (t == 0) nout[bz * 8 + tile] = red[0] + red[1] + red[2] + red[3];
}

// ---------------- rho_inv finalize: Gelfand log-sum over 13 norm slots -------------
__global__ __launch_bounds__(128) void rho_finalize(
    const float* __restrict__ partials, float* __restrict__ rho_inv)
{
  int bz = threadIdx.x;
  float a2 = 0.f, w = 1.0f;
  #pragma unroll
  for (int i2 = 0; i2 <= 12; i2++) {
    const float* p = partials + i2 * 1024 + bz * 8;
    float nm = p[0] + p[1] + p[2] + p[3] + p[4] + p[5] + p[6] + p[7];
    a2 += w * 0.5f * logf(nm);
    w *= 0.5f;
  }
  rho_inv[bz] = expf(-a2);
}

// ---------------- sigma: 1024-thread power iteration, LDS-cached bf16 W ------------
__device__ __forceinline__ float bsum1024(float x, float* red, int t)
{
  red[t] = x; __syncthreads();
  for (int off = 512; off > 0; off >>= 1) {
    if (t < off) red[t] += red[t + off];
    __syncthreads();
  }
  float r = red[0];
  __syncthreads();
  return r;
}

__global__ __launch_bounds__(1024) void sigma_kernel(
    const float* __restrict__ W, const float* __restrict__ u0, float* __restrict__ sigma)
{
  __shared__ short Wl[65536];
  __shared__ float u[256], v[256], red[1024];
  int t = threadIdx.x;
  int r = t & 255, seg = t >> 8;
  const float eps = 1e-12f;

  #pragma unroll
  for (int i = 0; i < 16; i++) {
    int idx = (i * 1024 + t) * 4;
    f4v w = *(const f4v*)(W + idx);
    short4v h;
    #pragma unroll
    for (int e = 0; e < 4; e++) h[e] = f2bf(w[e]);
    *(short4v*)&Wl[idx] = h;
  }

  float x = (t < 256) ? u0[t] : 0.f;
  float nrm = sqrtf(bsum1024(x * x, red, t));
  if (t < 256) u[t] = x / (nrm + eps);
  __syncthreads();

  for (int it = 0; it < 5; it++) {
    float sv = 0.f;
    #pragma unroll 8
    for (int j = 0; j < 64; j++) {
      int h = seg * 64 + j;
      sv = fmaf(bf2f(Wl[h * 256 + r]), u[h], sv);
    }
    red[t] = sv; __syncthreads();
    float vr = 0.f;
    if (t < 256) vr = red[t] + red[256 + t] + red[512 + t] + red[768 + t];
    __syncthreads();
    nrm = sqrtf(bsum1024(t < 256 ? vr * vr : 0.f, red, t));
    if (t < 256) v[t] = vr / (nrm + eps);
    __syncthreads();
    if (it < 4) {
      float su = 0.f;
      #pragma unroll
      for (int j = 0; j < 16; j++) {
        short4v w4 = *(const short4v*)&Wl[r * 256 + seg * 64 + j * 4];
        const float* vv = &v[seg * 64 + j * 4];
        su += bf2f(w4[0]) * vv[0] + bf2f(w4[1]) * vv[1]
            + bf2f(w4[2]) * vv[2] + bf2f(w4[3]) * vv[3];
      }
      red[t] = su; __syncthreads();
      float ur = 0.f;
      if (t < 256) ur = red[t] + red[256 + t] + red[512 + t] + red[768 + t];
      __syncthreads();
      nrm = sqrtf(bsum1024(t < 256 ? ur * ur : 0.f, red, t));
      if (t < 256) u[t] = ur / (nrm + eps);
      __syncthreads();
    }
  }

  float z = 0.f;
  #pragma unroll
  for (int j = 0; j < 16; j++) {
    f4v w = *(const f4v*)(W + r * 256 + seg * 64 + j * 4);
    const float* vv = &v[seg * 64 + j * 4];
    z += w[0] * vv[0] + w[1] * vv[1] + w[2] * vv[2] + w[3] * vv[3];
  }
  red[t] = z; __syncthreads();
  float zr = 0.f;
  if (t < 256) zr = red[t] + red[256 + t] + red[512 + t] + red[768 + t];
  __syncthreads();
  float zz = bsum1024(t < 256 ? zr * zr : 0.f, red, t);
  if (t == 0) sigma[0] = sqrtf(zz);
}

extern "C" void kernel_launch(void* const* d_in, const int* in_sizes, int n_in,
                              void* d_out, int out_size, void* d_ws, size_t ws_size,
                              hipStream_t stream)
{
  const float* x  = (const float*)d_in[0];
  const float* Wq = (const float*)d_in[1];
  const float* bq = (const float*)d_in[2];
  const float* Wk = (const float*)d_in[3];
  const float* bk = (const float*)d_in[4];
  const float* Wv = (const float*)d_in[5];
  const float* bv = (const float*)d_in[6];
  const float* u0 = (const float*)d_in[7];

  float* out  = (float*)d_out;
  float* out0 = out;             // q-split -> chain scratch -> weighted
  float* out1 = out + BIG;       // k-split -> chain scratch -> attention
  short* out0s = (short*)out0;
  short* out1s = (short*)out1;

  short* qhi = out0s;
  short* qlo = out0s + 32768LL * 256;
  short* khi = out1s;
  short* klo = out1s + 32768LL * 256;

  float* ws         = (float*)d_ws;
  float* scores_buf = ws;          // x-splits during proj; then [B,N,N] fp32 scores
  float* vals_buf   = ws + BIG;    // [B,N,D] RAW x@Wv^T (no sigma, no bias)
  float* partials   = ws + 2 * BIG;   // [13][1024]: 8 norm^2 partials per batch
  float* sigma      = partials + 13 * 1024;
  float* rho_inv    = sigma + 4;      // 128 floats
  short* wsplit     = (short*)(rho_inv + 128);  // [6][MAT] bf16 weight splits

  short* xhi = (short*)scores_buf;            // BIG shorts
  short* xlo = xhi + BIG;

  dim3 blk(256);

  // 0) pre-split weights AND x -> bf16 hi/lo (x-splits dead once proj done)
  split_inputs<<<dim3(4288, 1, 1), blk, 0, stream>>>(Wq, Wk, Wv, wsplit, x, xhi, xlo);

  // 1) projections: q,k split bf16 -> out0/out1; raw vals -> ws
  proj_qkv<<<dim3(1536, 1, 1), blk, 0, stream>>>(
      xhi, xlo, wsplit, bq, bk, qhi, qlo, khi, klo, vals_buf);

  // 2) scores = q @ k^T -> ws (fp32, overwrites x-splits), norm^2 -> slot 0
  scores_st<<<dim3(512, 1, 1), blk, 0, stream>>>(
      qhi, qlo, khi, klo, scores_buf, partials);

  // 3) sigma power iteration
  sigma_kernel<<<1, dim3(1024), 0, stream>>>(Wv, u0, sigma);

  // 4) squaring 1: S (fp32, split) -> bf16 M1 in out0s, norm slot 1
  sq_f32bf<<<dim3(512, 1, 1), blk, 0, stream>>>(scores_buf, out0s, partials, partials + 1024);

  // 5) squarings 2..11: bf16 chain, 1024 blocks (4/CU) for latency hiding
  const short* cin = out0s;
  for (int i = 0; i < 10; i++) {
    short* cout = (i & 1) ? out0s : out1s;
    sq_bf<true><<<dim3(1024, 1, 1), blk, 0, stream>>>(cin, cout,
        partials + (1 + i) * 1024, partials + (2 + i) * 1024);
    cin = cout;
  }
  // 6) squaring 12: norm only (slot 12)
  sq_bf<false><<<dim3(1024, 1, 1), blk, 0, stream>>>(cin, nullptr,
      partials + 11 * 1024, partials + 12 * 1024);

  // 7) rho_inv finalize (Gelfand log-sum, once per batch)
  rho_finalize<<<1, dim3(128), 0, stream>>>(partials, rho_inv);

  // 8) final: weighted = (S @ (vals/sigma + bv)) * rho_inv -> out0,
  //    attention = S * rho_inv -> out1 (A-staging). alpha = rho_inv[bz] (smode 2).
  gemm_mfma<false, true><<<dim3(512, 1, 1), blk, 0, stream>>>(
      scores_buf, vals_buf, out0, MAT, MAT, MAT, nullptr, rho_inv, 1, 2, nullptr,
      out1, nullptr, nullptr, nullptr, nullptr, nullptr, sigma, bv);
}

// Round 12
// 469.927 us; speedup vs baseline: 1.0609x; 1.0609x over previous
//
#include <hip/hip_runtime.h>
#include <hip/hip_bf16.h>

// B=128, N=256, D=H=256. out = [weighted (B*N*D), attention (B*N*N)] fp32.
// = Round-11 structure with the Gelfand chain shortened by one squaring:
//   the 2^-13-weighted log(n12) term is folded into n11's term (log n12 ~=
//   log n11 at convergence; worst-case output shift ~1e-3 << tolerance), and
//   the last squaring (M10 -> n11) is norm-only (no M11 write-out).
//   Chain: sq_f32bf + 9x sq_bf<true> + sq_bf<false>  (was +10 +1).
// proj_qkv: no prefetch (62-65 µs across 3 runs vs 71-73 with). scores_st:
// r10 prefetch version. Final: smode-2 gemm_mfma; rho via rho_finalize (x1.5
// last-term weight).

#define NB 128
#define MAT 65536
#define BIG 8388608LL

typedef __attribute__((ext_vector_type(4))) float floatx4;
typedef __attribute__((ext_vector_type(4))) float f4v;
typedef __attribute__((ext_vector_type(8))) short short8v;
typedef __attribute__((ext_vector_type(4))) short short4v;

__device__ __forceinline__ short f2bf(float x) {
  union { float f; unsigned u; } v; v.f = x;
  unsigned r = v.u + 0x7fff + ((v.u >> 16) & 1);
  return (short)(r >> 16);
}
__device__ __forceinline__ float bf2f(short h) {
  union { unsigned u; float f; } v; v.u = ((unsigned)(unsigned short)h) << 16; return v.f;
}

// ---------------- generic split-bf16 GEMM (FINAL GEMM only) ------------------------
template<bool TB, bool BATCHED>
__global__ __launch_bounds__(256) void gemm_mfma(
    const float* __restrict__ A, const float* __restrict__ B, float* __restrict__ C,
    long long sA, long long sB, long long sC,
    const float* __restrict__ bias,
    const float* __restrict__ scale_ptr, int sstride, int smode,
    float* __restrict__ norm_out,
    float* __restrict__ att_out,
    const float* __restrict__ B2, const float* __restrict__ bias2, float* __restrict__ C2,
    const float* __restrict__ B3, float* __restrict__ C3,
    const float* __restrict__ bsc, const float* __restrict__ bsb)
{
  __shared__ short sAhi[128 * 32], sAlo[128 * 32];
  __shared__ short sBhi[128 * 40], sBlo[128 * 40];

  int bz, m0, n0;
  if constexpr (BATCHED) {
    int lin = blockIdx.x;
    int xcd = lin & 7;
    int s = lin >> 3;
    bz = xcd * 16 + (s >> 2);
    int tile = s & 3;
    m0 = (tile >> 1) * 128;
    n0 = (tile & 1) * 128;
  } else {
    bz = 0;
    m0 = blockIdx.y * 128;
    n0 = (blockIdx.x & 1) * 128;
    int sel = blockIdx.x >> 1;
    if (sel == 1) { B = B2; bias = bias2; C = C2; }
    else if (sel == 2) { B = B3; bias = nullptr; C = C3; }
  }
  A += (long long)bz * sA;
  B += (long long)bz * sB;
  C += (long long)bz * sC;

  const int t = threadIdx.x;
  const int lane = t & 63;
  const int wave = t >> 6;
  const int wm = wave >> 1, wn = wave & 1;
  const int q = lane >> 4, c16 = lane & 15;

  float alpha = 1.0f;
  if (smode == 1) alpha = 1.0f / scale_ptr[bz * sstride];
  else if (smode == 2) alpha = scale_ptr[bz * sstride];

  float rinv_att = alpha;
  const bool do_att = (att_out != nullptr) && (n0 == 0);

  float binv = 1.0f;
  if (bsc) binv = 1.0f / bsc[0];

  floatx4 acc[4][4];
  #pragma unroll
  for (int i = 0; i < 4; i++)
    #pragma unroll
    for (int j = 0; j < 4; j++)
      acc[i][j] = (floatx4){0.f, 0.f, 0.f, 0.f};

  for (int k0 = 0; k0 < 256; k0 += 32) {
    #pragma unroll
    for (int i = 0; i < 4; i++) {
      int f = t + i * 256;
      int row = f >> 3, c4 = f & 7;
      f4v v = *(const f4v*)(A + (long long)(m0 + row) * 256 + k0 + c4 * 4);
      if (do_att)
        *(f4v*)(att_out + (long long)bz * MAT + (long long)(m0 + row) * 256 + k0 + c4 * 4)
            = v * rinv_att;
      short4v h, l;
      #pragma unroll
      for (int e = 0; e < 4; e++) {
        short hh = f2bf(v[e]);
        h[e] = hh;
        l[e] = f2bf(v[e] - bf2f(hh));
      }
      *(short4v*)&sAhi[row * 32 + c4 * 4] = h;
      *(short4v*)&sAlo[row * 32 + c4 * 4] = l;
    }
    if constexpr (TB) {
      #pragma unroll
      for (int i = 0; i < 4; i++) {
        int f = t + i * 256;
        int row = f >> 3, c4 = f & 7;
        f4v v = *(const f4v*)(B + (long long)(n0 + row) * 256 + k0 + c4 * 4);
        short4v h, l;
        #pragma unroll
        for (int e = 0; e < 4; e++) {
          short hh = f2bf(v[e]);
          h[e] = hh;
          l[e] = f2bf(v[e] - bf2f(hh));
        }
        *(short4v*)&sBhi[row * 40 + c4 * 4] = h;
        *(short4v*)&sBlo[row * 40 + c4 * 4] = l;
      }
      __syncthreads();
    } else {
      __shared__ float sT[32 * 132];
      #pragma unroll
      for (int i = 0; i < 4; i++) {
        int f = t + i * 256;
        int kk = f >> 5, n4 = f & 31;
        f4v v = *(const f4v*)(B + (long long)(k0 + kk) * 256 + n0 + n4 * 4);
        if (bsb) {
          #pragma unroll
          for (int e = 0; e < 4; e++) v[e] = v[e] * binv + bsb[n0 + n4 * 4 + e];
        }
        *(f4v*)&sT[kk * 132 + n4 * 4] = v;
      }
      __syncthreads();
      int n = t & 127, kh = t >> 7;
      short8v h0, h1, l0, l1;
      #pragma unroll
      for (int j = 0; j < 8; j++) {
        float x0 = sT[(kh * 16 + j) * 132 + n];
        float x1 = sT[(kh * 16 + 8 + j) * 132 + n];
        short a0 = f2bf(x0), a1 = f2bf(x1);
        h0[j] = a0; l0[j] = f2bf(x0 - bf2f(a0));
        h1[j] = a1; l1[j] = f2bf(x1 - bf2f(a1));
      }
      *(short8v*)&sBhi[n * 40 + kh * 16] = h0;
      *(short8v*)&sBhi[n * 40 + kh * 16 + 8] = h1;
      *(short8v*)&sBlo[n * 40 + kh * 16] = l0;
      *(short8v*)&sBlo[n * 40 + kh * 16 + 8] = l1;
      __syncthreads();
    }

    short8v ah[4], al[4], bh[4], bl[4];
    #pragma unroll
    for (int fi = 0; fi < 4; fi++) {
      int r = wm * 64 + fi * 16 + c16;
      ah[fi] = *(short8v*)&sAhi[r * 32 + q * 8];
      al[fi] = *(short8v*)&sAlo[r * 32 + q * 8];
    }
    #pragma unroll
    for (int fj = 0; fj < 4; fj++) {
      int r = wn * 64 + fj * 16 + c16;
      bh[fj] = *(short8v*)&sBhi[r * 40 + q * 8];
      bl[fj] = *(short8v*)&sBlo[r * 40 + q * 8];
    }
    #pragma unroll
    for (int fi = 0; fi < 4; fi++)
      #pragma unroll
      for (int fj = 0; fj < 4; fj++) {
        acc[fi][fj] = __builtin_amdgcn_mfma_f32_16x16x32_bf16(al[fi], bh[fj], acc[fi][fj], 0, 0, 0);
        acc[fi][fj] = __builtin_amdgcn_mfma_f32_16x16x32_bf16(ah[fi], bl[fj], acc[fi][fj], 0, 0, 0);
        acc[fi][fj] = __builtin_amdgcn_mfma_f32_16x16x32_bf16(ah[fi], bh[fj], acc[fi][fj], 0, 0, 0);
      }
    __syncthreads();
  }

  float ssq = 0.f;
  #pragma unroll
  for (int fi = 0; fi < 4; fi++) {
    #pragma unroll
    for (int fj = 0; fj < 4; fj++) {
      int col = n0 + wn * 64 + fj * 16 + c16;
      float bb = bias ? bias[col] : 0.f;
      #pragma unroll
      for (int r = 0; r < 4; r++) {
        int row = m0 + wm * 64 + fi * 16 + q * 4 + r;
        float v = acc[fi][fj][r] * alpha + bb;
        C[(long long)row * 256 + col] = v;
        ssq += v * v;
      }
    }
  }

  if (norm_out) {
    float* red = (float*)sAhi;
    red[t] = ssq;
    __syncthreads();
    for (int off = 128; off > 0; off >>= 1) {
      if (t < off) red[t] += red[t + off];
      __syncthreads();
    }
    if (t == 0) {
      int tl = ((m0 >> 7) << 1) | (n0 >> 7);
      norm_out[bz * 4 + tl] = red[0];
    }
  }
}

// ---------------- split inputs: Wq/Wk/Wv and x -> bf16 hi/lo -----------------------
__global__ __launch_bounds__(256) void split_inputs(
    const float* __restrict__ Wq, const float* __restrict__ Wk,
    const float* __restrict__ Wv, short* __restrict__ ws6,
    const float* __restrict__ x, short* __restrict__ xhi, short* __restrict__ xlo)
{
  int b = blockIdx.x;
  int t = threadIdx.x;
  if (b < 192) {
    int gid = b * 256 + t;
    int m = gid >> 14;                          // 0..2
    int off = (gid & 16383) * 4;
    const float* src = (m == 0) ? Wq : (m == 1) ? Wk : Wv;
    f4v v = *(const f4v*)(src + off);
    short4v h, l;
    #pragma unroll
    for (int e = 0; e < 4; e++) {
      short hh = f2bf(v[e]);
      h[e] = hh;
      l[e] = f2bf(v[e] - bf2f(hh));
    }
    *(short4v*)&ws6[(long long)(m * 2) * MAT + off] = h;
    *(short4v*)&ws6[(long long)(m * 2 + 1) * MAT + off] = l;
  } else {
    long long off = ((long long)(b - 192) * 256 + t) * 8;
    #pragma unroll
    for (int half = 0; half < 2; half++) {
      f4v v = *(const f4v*)(x + off + half * 4);
      short4v h, l;
      #pragma unroll
      for (int e = 0; e < 4; e++) {
        short hh = f2bf(v[e]);
        h[e] = hh;
        l[e] = f2bf(v[e] - bf2f(hh));
      }
      *(short4v*)&xhi[off + half * 4] = h;
      *(short4v*)&xlo[off + half * 4] = l;
    }
  }
}

// ---------------- projections: XCD-grouped, copy-staged A AND B (NO prefetch) ------
// 1536 blocks: xcd = lin&7, idx = lin>>3; m_tile = xcd*32 + idx/6; role idx%6.
// L2-hot operands — A/B across 3 runs showed register prefetch COSTS ~7 µs here.
__global__ __launch_bounds__(256) void proj_qkv(
    const short* __restrict__ xhi, const short* __restrict__ xlo,
    const short* __restrict__ wsp,
    const float* __restrict__ bq, const float* __restrict__ bk,
    short* __restrict__ qhi, short* __restrict__ qlo,
    short* __restrict__ khi, short* __restrict__ klo,
    float* __restrict__ vals)
{
  __shared__ short sAhi[128 * 32], sAlo[128 * 32];
  __shared__ short sBhi[128 * 40], sBlo[128 * 40];

  const int lin = blockIdx.x;
  const int xcd = lin & 7;
  const int idx = lin >> 3;
  const int mloc = idx / 6;
  const int s6 = idx - mloc * 6;
  const int m0 = (xcd * 32 + mloc) * 128;
  const int sel = s6 >> 1;
  const int n0 = (s6 & 1) * 128;

  const short* wb_hi = wsp + (long long)(sel * 2) * MAT;
  const short* wb_lo = wsp + (long long)(sel * 2 + 1) * MAT;

  const int t = threadIdx.x;
  const int lane = t & 63;
  const int wave = t >> 6;
  const int wm = wave >> 1, wn = wave & 1;
  const int q = lane >> 4, c16 = lane & 15;

  floatx4 acc[4][4];
  #pragma unroll
  for (int i = 0; i < 4; i++)
    #pragma unroll
    for (int j = 0; j < 4; j++)
      acc[i][j] = (floatx4){0.f, 0.f, 0.f, 0.f};

  for (int k0 = 0; k0 < 256; k0 += 32) {
    #pragma unroll
    for (int i = 0; i < 2; i++) {
      int chunk = t + i * 256;                 // 0..511
      int row = chunk >> 2, c8 = chunk & 3;
      long long ga = (long long)(m0 + row) * 256 + k0 + c8 * 8;
      *(short8v*)&sAhi[row * 32 + c8 * 8] = *(const short8v*)(xhi + ga);
      *(short8v*)&sAlo[row * 32 + c8 * 8] = *(const short8v*)(xlo + ga);
    }
    #pragma unroll
    for (int i = 0; i < 2; i++) {
      int chunk = t + i * 256;
      int row = chunk >> 2, c8 = chunk & 3;
      long long gr = (long long)(n0 + row) * 256 + k0 + c8 * 8;
      *(short8v*)&sBhi[row * 40 + c8 * 8] = *(const short8v*)(wb_hi + gr);
      *(short8v*)&sBlo[row * 40 + c8 * 8] = *(const short8v*)(wb_lo + gr);
    }
    __syncthreads();

    short8v ah[4], al[4], bh[4], bl[4];
    #pragma unroll
    for (int fi = 0; fi < 4; fi++) {
      int r = wm * 64 + fi * 16 + c16;
      ah[fi] = *(short8v*)&sAhi[r * 32 + q * 8];
      al[fi] = *(short8v*)&sAlo[r * 32 + q * 8];
    }
    #pragma unroll
    for (int fj = 0; fj < 4; fj++) {
      int r = wn * 64 + fj * 16 + c16;
      bh[fj] = *(short8v*)&sBhi[r * 40 + q * 8];
      bl[fj] = *(short8v*)&sBlo[r * 40 + q * 8];
    }
    #pragma unroll
    for (int fi = 0; fi < 4; fi++)
      #pragma unroll
      for (int fj = 0; fj < 4; fj++) {
        acc[fi][fj] = __builtin_amdgcn_mfma_f32_16x16x32_bf16(al[fi], bh[fj], acc[fi][fj], 0, 0, 0);
        acc[fi][fj] = __builtin_amdgcn_mfma_f32_16x16x32_bf16(ah[fi], bl[fj], acc[fi][fj], 0, 0, 0);
        acc[fi][fj] = __builtin_amdgcn_mfma_f32_16x16x32_bf16(ah[fi], bh[fj], acc[fi][fj], 0, 0, 0);
      }
    __syncthreads();
  }

  if (sel < 2) {
    short* ohi = sel ? khi : qhi;
    short* olo = sel ? klo : qlo;
    const float* bb = sel ? bk : bq;
    #pragma unroll
    for (int fi = 0; fi < 4; fi++)
      #pragma unroll
      for (int fj = 0; fj < 4; fj++) {
        int col = n0 + wn * 64 + fj * 16 + c16;
        float b = bb[col];
        #pragma unroll
        for (int r = 0; r < 4; r++) {
          long long row = m0 + wm * 64 + fi * 16 + q * 4 + r;
          float v = acc[fi][fj][r] + b;
          short h = f2bf(v);
          ohi[row * 256 + col] = h;
          olo[row * 256 + col] = f2bf(v - bf2f(h));
        }
      }
  } else {
    #pragma unroll
    for (int fi = 0; fi < 4; fi++)
      #pragma unroll
      for (int fj = 0; fj < 4; fj++) {
        int col = n0 + wn * 64 + fj * 16 + c16;
        #pragma unroll
        for (int r = 0; r < 4; r++) {
          long long row = m0 + wm * 64 + fi * 16 + q * 4 + r;
          vals[row * 256 + col] = acc[fi][fj][r];
        }
      }
  }
}

// ---------------- scores = q @ k^T: copy-staged + register prefetch ----------------
// q/k splits are 8.4 MB/XCD (> 4 MB L2) -> HBM-latency bound.
// norm slot 8-wide: writes bz*8+tile, zeros 4..7.
__global__ __launch_bounds__(256) void scores_st(
    const short* __restrict__ qhi, const short* __restrict__ qlo,
    const short* __restrict__ khi, const short* __restrict__ klo,
    float* __restrict__ S, float* __restrict__ norm_out)
{
  __shared__ short sAhi[128 * 32], sAlo[128 * 32];
  __shared__ short sBhi[128 * 40], sBlo[128 * 40];
  __shared__ float red[256];

  const int lin = blockIdx.x;
  const int xcd = lin & 7, s = lin >> 3;
  const int bz = xcd * 16 + (s >> 2);
  const int tile = s & 3;
  const int m0 = (tile >> 1) * 128, n0 = (tile & 1) * 128;

  const int t = threadIdx.x;
  const int lane = t & 63;
  const int wave = t >> 6;
  const int wm = wave >> 1, wn = wave & 1;
  const int q = lane >> 4, c16 = lane & 15;
  const int srow = t >> 2, sc8 = (t & 3) * 8;

  floatx4 acc[4][4];
  #pragma unroll
  for (int i = 0; i < 4; i++)
    #pragma unroll
    for (int j = 0; j < 4; j++)
      acc[i][j] = (floatx4){0.f, 0.f, 0.f, 0.f};

  const long long abase = (long long)(bz * 256 + m0) * 256;
  const long long bbase = (long long)(bz * 256 + n0) * 256;

  short8v pAh[2], pAl[2], pBh[2], pBl[2];
  {
    #pragma unroll
    for (int i = 0; i < 2; i++) {
      long long ga = abase + (long long)(srow + i * 64) * 256 + sc8;
      long long gb = bbase + (long long)(srow + i * 64) * 256 + sc8;
      pAh[i] = *(const short8v*)(qhi + ga);
      pAl[i] = *(const short8v*)(qlo + ga);
      pBh[i] = *(const short8v*)(khi + gb);
      pBl[i] = *(const short8v*)(klo + gb);
    }
  }

  for (int k0 = 0; k0 < 256; k0 += 32) {
    #pragma unroll
    for (int i = 0; i < 2; i++) {
      int row = srow + i * 64;
      *(short8v*)&sAhi[row * 32 + sc8] = pAh[i];
      *(short8v*)&sAlo[row * 32 + sc8] = pAl[i];
      *(short8v*)&sBhi[row * 40 + sc8] = pBh[i];
      *(short8v*)&sBlo[row * 40 + sc8] = pBl[i];
    }
    __syncthreads();

    if (k0 < 224) {
      int kn = k0 + 32;
      #pragma unroll
      for (int i = 0; i < 2; i++) {
        long long ga = abase + (long long)(srow + i * 64) * 256 + kn + sc8;
        long long gb = bbase + (long long)(srow + i * 64) * 256 + kn + sc8;
        pAh[i] = *(const short8v*)(qhi + ga);
        pAl[i] = *(const short8v*)(qlo + ga);
        pBh[i] = *(const short8v*)(khi + gb);
        pBl[i] = *(const short8v*)(klo + gb);
      }
    }

    short8v ah[4], al[4], bh[4], bl[4];
    #pragma unroll
    for (int fi = 0; fi < 4; fi++) {
      int r = wm * 64 + fi * 16 + c16;
      ah[fi] = *(short8v*)&sAhi[r * 32 + q * 8];
      al[fi] = *(short8v*)&sAlo[r * 32 + q * 8];
    }
    #pragma unroll
    for (int fj = 0; fj < 4; fj++) {
      int r = wn * 64 + fj * 16 + c16;
      bh[fj] = *(short8v*)&sBhi[r * 40 + q * 8];
      bl[fj] = *(short8v*)&sBlo[r * 40 + q * 8];
    }
    #pragma unroll
    for (int fi = 0; fi < 4; fi++)
      #pragma unroll
      for (int fj = 0; fj < 4; fj++) {
        acc[fi][fj] = __builtin_amdgcn_mfma_f32_16x16x32_bf16(al[fi], bh[fj], acc[fi][fj], 0, 0, 0);
        acc[fi][fj] = __builtin_amdgcn_mfma_f32_16x16x32_bf16(ah[fi], bl[fj], acc[fi][fj], 0, 0, 0);
        acc[fi][fj] = __builtin_amdgcn_mfma_f32_16x16x32_bf16(ah[fi], bh[fj], acc[fi][fj], 0, 0, 0);
      }
    __syncthreads();
  }

  float* C = S + (long long)bz * MAT;
  float ssq = 0.f;
  #pragma unroll
  for (int fi = 0; fi < 4; fi++)
    #pragma unroll
    for (int fj = 0; fj < 4; fj++) {
      int col = n0 + wn * 64 + fj * 16 + c16;
      #pragma unroll
      for (int r = 0; r < 4; r++) {
        int row = m0 + wm * 64 + fi * 16 + q * 4 + r;
        float v = acc[fi][fj][r];
        C[(long long)row * 256 + col] = v;
        ssq += v * v;
      }
    }

  red[t] = ssq;
  __syncthreads();
  for (int o = 128; o > 0; o >>= 1) {
    if (t < o) red[t] += red[t + o];
    __syncthreads();
  }
  if (t == 0) norm_out[bz * 8 + tile] = red[0];
  if (t == 1) norm_out[bz * 8 + 4 + tile] = 0.f;
}

// ---------------- chain epilogue (sq_f32bf): alpha*acc -> bf16 tile + norm ---------
__device__ __forceinline__ void chain_epilogue(
    short* LB, float* red, floatx4 (&acc)[4][4], float alpha,
    int m0, int n0, int wm, int wn, int q, int c16, int t,
    short* __restrict__ Mout,
    float* __restrict__ nout, int nidx, bool write_out)
{
  __syncthreads();
  float ssq = 0.f;
  #pragma unroll
  for (int fi = 0; fi < 4; fi++)
    #pragma unroll
    for (int fj = 0; fj < 4; fj++) {
      int lcol = wn * 64 + fj * 16 + c16;
      #pragma unroll
      for (int r = 0; r < 4; r++) {
        int lrow = wm * 64 + fi * 16 + q * 4 + r;
        float v = acc[fi][fj][r] * alpha;
        ssq += v * v;
        if (write_out) LB[lrow * 128 + lcol] = f2bf(v);
      }
    }

  if (write_out) {
    __syncthreads();
    int lr = t >> 1, off = (t & 1) * 64;
    #pragma unroll
    for (int jc = 0; jc < 8; jc++)
      *(short8v*)(Mout + (long long)(m0 + lr) * 256 + n0 + off + jc * 8)
          = *(const short8v*)&LB[lr * 128 + off + jc * 8];
  }

  red[t] = ssq;
  __syncthreads();
  for (int off2 = 128; off2 > 0; off2 >>= 1) {
    if (t < off2) red[t] += red[t + off2];
    __syncthreads();
  }
  if (t == 0) nout[nidx] = red[0];
}

// ---------------- squaring 1: fp32 S (split 3-MFMA) -> bf16 M ----------------------
// norm slot 8-wide (writes bz*8+tile, zeros 4..7).
__global__ __launch_bounds__(256) void sq_f32bf(
    const float* __restrict__ S, short* __restrict__ Mo,
    const float* __restrict__ nprev, float* __restrict__ nout)
{
  __shared__ short SM[18432];
  __shared__ float sT[32 * 132];
  __shared__ float red[256];
  short* sAhi = SM;
  short* sAlo = SM + 4096;
  short* sBhi = SM + 8192;
  short* sBlo = SM + 13312;

  int lin = blockIdx.x;
  int xcd = lin & 7, s = lin >> 3;
  int bz = xcd * 16 + (s >> 2);
  int tile = s & 3;
  int m0 = (tile >> 1) * 128, n0 = (tile & 1) * 128;
  const float* A = S + (long long)bz * MAT;

  const int t = threadIdx.x;
  const int lane = t & 63;
  const int wave = t >> 6;
  const int wm = wave >> 1, wn = wave & 1;
  const int q = lane >> 4, c16 = lane & 15;

  floatx4 acc[4][4];
  #pragma unroll
  for (int i = 0; i < 4; i++)
    #pragma unroll
    for (int j = 0; j < 4; j++)
      acc[i][j] = (floatx4){0.f, 0.f, 0.f, 0.f};

  for (int k0 = 0; k0 < 256; k0 += 32) {
    #pragma unroll
    for (int i = 0; i < 4; i++) {
      int f = t + i * 256;
      int row = f >> 3, c4 = f & 7;
      f4v v = *(const f4v*)(A + (long long)(m0 + row) * 256 + k0 + c4 * 4);
      short4v h, l;
      #pragma unroll
      for (int e = 0; e < 4; e++) {
        short hh = f2bf(v[e]);
        h[e] = hh;
        l[e] = f2bf(v[e] - bf2f(hh));
      }
      *(short4v*)&sAhi[row * 32 + c4 * 4] = h;
      *(short4v*)&sAlo[row * 32 + c4 * 4] = l;
    }
    #pragma unroll
    for (int i = 0; i < 4; i++) {
      int f = t + i * 256;
      int kk = f >> 5, n4 = f & 31;
      f4v v = *(const f4v*)(A + (long long)(k0 + kk) * 256 + n0 + n4 * 4);
      *(f4v*)&sT[kk * 132 + n4 * 4] = v;
    }
    __syncthreads();
    {
      int n = t & 127, kh = t >> 7;
      short8v h0, h1, l0, l1;
      #pragma unroll
      for (int j = 0; j < 8; j++) {
        float x0 = sT[(kh * 16 + j) * 132 + n];
        float x1 = sT[(kh * 16 + 8 + j) * 132 + n];
        short a0 = f2bf(x0), a1 = f2bf(x1);
        h0[j] = a0; l0[j] = f2bf(x0 - bf2f(a0));
        h1[j] = a1; l1[j] = f2bf(x1 - bf2f(a1));
      }
      *(short8v*)&sBhi[n * 40 + kh * 16] = h0;
      *(short8v*)&sBhi[n * 40 + kh * 16 + 8] = h1;
      *(short8v*)&sBlo[n * 40 + kh * 16] = l0;
      *(short8v*)&sBlo[n * 40 + kh * 16 + 8] = l1;
    }
    __syncthreads();

    short8v ah[4], al[4], bh[4], bl[4];
    #pragma unroll
    for (int fi = 0; fi < 4; fi++) {
      int r = wm * 64 + fi * 16 + c16;
      ah[fi] = *(short8v*)&sAhi[r * 32 + q * 8];
      al[fi] = *(short8v*)&sAlo[r * 32 + q * 8];
    }
    #pragma unroll
    for (int fj = 0; fj < 4; fj++) {
      int r = wn * 64 + fj * 16 + c16;
      bh[fj] = *(short8v*)&sBhi[r * 40 + q * 8];
      bl[fj] = *(short8v*)&sBlo[r * 40 + q * 8];
    }
    #pragma unroll
    for (int fi = 0; fi < 4; fi++)
      #pragma unroll
      for (int fj = 0; fj < 4; fj++) {
        acc[fi][fj] = __builtin_amdgcn_mfma_f32_16x16x32_bf16(al[fi], bh[fj], acc[fi][fj], 0, 0, 0);
        acc[fi][fj] = __builtin_amdgcn_mfma_f32_16x16x32_bf16(ah[fi], bl[fj], acc[fi][fj], 0, 0, 0);
        acc[fi][fj] = __builtin_amdgcn_mfma_f32_16x16x32_bf16(ah[fi], bh[fj], acc[fi][fj], 0, 0, 0);
      }
    __syncthreads();
  }

  const float* p = nprev + bz * 8;
  float alpha = 1.0f / (p[0] + p[1] + p[2] + p[3]);
  chain_epilogue(SM, red, acc, alpha, m0, n0, wm, wn, q, c16, t,
                 Mo + (long long)bz * MAT, nout, bz * 8 + tile, true);
  if (t == 1) nout[bz * 8 + 4 + tile] = 0.f;
}

// ---------------- squarings 2..: 1024 blocks, 64x128 tiles, dbuf + prefetch --------
template<bool WRITE_OUT>
__global__ __launch_bounds__(256) void sq_bf(
    const short* __restrict__ Mi, short* __restrict__ Mo,
    const float* __restrict__ nprev, float* __restrict__ nout)
{
  __shared__ short SMEM[9216];    // Bs dbuf = 2 x [128][36]; epilogue LB 64x128 fits
  __shared__ float red[4];
  short* BsA = SMEM;
  short* BsB = SMEM + 4608;

  int lin = blockIdx.x;
  int xcd = lin & 7, s = lin >> 3;     // s 0..127
  int bz = xcd * 16 + (s >> 3);
  int tile = s & 7;
  int m0 = (tile >> 1) * 64, n0 = (tile & 1) * 128;

  const short* A = Mi + (long long)bz * MAT;

  const int t = threadIdx.x;
  const int lane = t & 63;
  const int wave = t >> 6;
  const int wm = wave >> 1, wn = wave & 1;   // wave tile 32x64
  const int q = lane >> 4, c16 = lane & 15;
  const int g = t >> 5, cc = t & 31;   // staging: 8 k-groups x 32 col-chunks

  floatx4 acc[2][4];
  #pragma unroll
  for (int i = 0; i < 2; i++)
    #pragma unroll
    for (int j = 0; j < 4; j++)
      acc[i][j] = (floatx4){0.f, 0.f, 0.f, 0.f};

  short4v r0 = *(const short4v*)(A + (long long)(g * 4 + 0) * 256 + n0 + cc * 4);
  short4v r1 = *(const short4v*)(A + (long long)(g * 4 + 1) * 256 + n0 + cc * 4);
  short4v r2 = *(const short4v*)(A + (long long)(g * 4 + 2) * 256 + n0 + cc * 4);
  short4v r3 = *(const short4v*)(A + (long long)(g * 4 + 3) * 256 + n0 + cc * 4);

  for (int k0 = 0; k0 < 256; k0 += 32) {
    short* Bw = ((k0 >> 5) & 1) ? BsB : BsA;
    #pragma unroll
    for (int j = 0; j < 4; j++) {
      short4v w4 = (short4v){r0[j], r1[j], r2[j], r3[j]};
      *(short4v*)&Bw[(cc * 4 + j) * 36 + g * 4] = w4;
    }
    __syncthreads();

    if (k0 < 224) {
      int kn = k0 + 32;
      r0 = *(const short4v*)(A + (long long)(kn + g * 4 + 0) * 256 + n0 + cc * 4);
      r1 = *(const short4v*)(A + (long long)(kn + g * 4 + 1) * 256 + n0 + cc * 4);
      r2 = *(const short4v*)(A + (long long)(kn + g * 4 + 2) * 256 + n0 + cc * 4);
      r3 = *(const short4v*)(A + (long long)(kn + g * 4 + 3) * 256 + n0 + cc * 4);
    }

    short8v a[2], b[4];
    #pragma unroll
    for (int fi = 0; fi < 2; fi++)
      a[fi] = *(const short8v*)(A + (long long)(m0 + wm * 32 + fi * 16 + c16) * 256 + k0 + q * 8);
    #pragma unroll
    for (int fj = 0; fj < 4; fj++) {
      int n = wn * 64 + fj * 16 + c16;
      short4v lo = *(const short4v*)&Bw[n * 36 + q * 8];
      short4v hi = *(const short4v*)&Bw[n * 36 + q * 8 + 4];
      b[fj] = __builtin_shufflevector(lo, hi, 0, 1, 2, 3, 4, 5, 6, 7);
    }
    #pragma unroll
    for (int fi = 0; fi < 2; fi++)
      #pragma unroll
      for (int fj = 0; fj < 4; fj++)
        acc[fi][fj] = __builtin_amdgcn_mfma_f32_16x16x32_bf16(a[fi], b[fj], acc[fi][fj], 0, 0, 0);
  }

  const float* p = nprev + bz * 8;
  float alpha = 1.0f / (p[0] + p[1] + p[2] + p[3] + p[4] + p[5] + p[6] + p[7]);

  __syncthreads();   // all Bw reads of the k-loop consumed before LB reuse
  short* LB = SMEM;
  float ssq = 0.f;
  #pragma unroll
  for (int fi = 0; fi < 2; fi++)
    #pragma unroll
    for (int fj = 0; fj < 4; fj++) {
      int lcol = wn * 64 + fj * 16 + c16;
      #pragma unroll
      for (int r = 0; r < 4; r++) {
        int lrow = wm * 32 + fi * 16 + q * 4 + r;
        float v = acc[fi][fj][r] * alpha;
        ssq += v * v;
        if (WRITE_OUT) LB[lrow * 128 + lcol] = f2bf(v);
      }
    }

  if (WRITE_OUT) {
    __syncthreads();
    int lr = t >> 2, off = (t & 3) * 32;
    #pragma unroll
    for (int jc = 0; jc < 4; jc++)
      *(short8v*)(Mo + (long long)bz * MAT + (long long)(m0 + lr) * 256 + n0 + off + jc * 8)
          = *(const short8v*)&LB[lr * 128 + off + jc * 8];
  }

  #pragma unroll
  for (int off2 = 32; off2 > 0; off2 >>= 1)
    ssq += __shfl_xor(ssq, off2, 64);
  if (lane == 0) red[wave] = ssq;
  __syncthreads();
  if (t == 0) nout[bz * 8 + tile] = red[0] + red[1] + red[2] + red[3];
}

// ---------------- rho_inv finalize: Gelfand log-sum over 12 norm slots -------------
// Term 12 folded into term 11 (log n12 ~= log n11 at convergence): weight x1.5.
__global__ __launch_bounds__(128) void rho_finalize(
    const float* __restrict__ partials, float* __restrict__ rho_inv)
{
  int bz = threadIdx.x;
  float a2 = 0.f, w = 1.0f;
  #pragma unroll
  for (int i2 = 0; i2 <= 11; i2++) {
    const float* p = partials + i2 * 1024 + bz * 8;
    float nm = p[0] + p[1] + p[2] + p[3] + p[4] + p[5] + p[6] + p[7];
    float term = w * 0.5f * logf(nm);
    a2 += (i2 == 11) ? term * 1.5f : term;
    w *= 0.5f;
  }
  rho_inv[bz] = expf(-a2);
}

// ---------------- sigma: 1024-thread power iteration, LDS-cached bf16 W ------------
__device__ __forceinline__ float bsum1024(float x, float* red, int t)
{
  red[t] = x; __syncthreads();
  for (int off = 512; off > 0; off >>= 1) {
    if (t < off) red[t] += red[t + off];
    __syncthreads();
  }
  float r = red[0];
  __syncthreads();
  return r;
}

__global__ __launch_bounds__(1024) void sigma_kernel(
    const float* __restrict__ W, const float* __restrict__ u0, float* __restrict__ sigma)
{
  __shared__ short Wl[65536];
  __shared__ float u[256], v[256], red[1024];
  int t = threadIdx.x;
  int r = t & 255, seg = t >> 8;
  const float eps = 1e-12f;

  #pragma unroll
  for (int i = 0; i < 16; i++) {
    int idx = (i * 1024 + t) * 4;
    f4v w = *(const f4v*)(W + idx);
    short4v h;
    #pragma unroll
    for (int e = 0; e < 4; e++) h[e] = f2bf(w[e]);
    *(short4v*)&Wl[idx] = h;
  }

  float x = (t < 256) ? u0[t] : 0.f;
  float nrm = sqrtf(bsum1024(x * x, red, t));
  if (t < 256) u[t] = x / (nrm + eps);
  __syncthreads();

  for (int it = 0; it < 5; it++) {
    float sv = 0.f;
    #pragma unroll 8
    for (int j = 0; j < 64; j++) {
      int h = seg * 64 + j;
      sv = fmaf(bf2f(Wl[h * 256 + r]), u[h], sv);
    }
    red[t] = sv; __syncthreads();
    float vr = 0.f;
    if (t < 256) vr = red[t] + red[256 + t] + red[512 + t] + red[768 + t];
    __syncthreads();
    nrm = sqrtf(bsum1024(t < 256 ? vr * vr : 0.f, red, t));
    if (t < 256) v[t] = vr / (nrm + eps);
    __syncthreads();
    if (it < 4) {
      float su = 0.f;
      #pragma unroll
      for (int j = 0; j < 16; j++) {
        short4v w4 = *(const short4v*)&Wl[r * 256 + seg * 64 + j * 4];
        const float* vv = &v[seg * 64 + j * 4];
        su += bf2f(w4[0]) * vv[0] + bf2f(w4[1]) * vv[1]
            + bf2f(w4[2]) * vv[2] + bf2f(w4[3]) * vv[3];
      }
      red[t] = su; __syncthreads();
      float ur = 0.f;
      if (t < 256) ur = red[t] + red[256 + t] + red[512 + t] + red[768 + t];
      __syncthreads();
      nrm = sqrtf(bsum1024(t < 256 ? ur * ur : 0.f, red, t));
      if (t < 256) u[t] = ur / (nrm + eps);
      __syncthreads();
    }
  }

  float z = 0.f;
  #pragma unroll
  for (int j = 0; j < 16; j++) {
    f4v w = *(const f4v*)(W + r * 256 + seg * 64 + j * 4);
    const float* vv = &v[seg * 64 + j * 4];
    z += w[0] * vv[0] + w[1] * vv[1] + w[2] * vv[2] + w[3] * vv[3];
  }
  red[t] = z; __syncthreads();
  float zr = 0.f;
  if (t < 256) zr = red[t] + red[256 + t] + red[512 + t] + red[768 + t];
  __syncthreads();
  float zz = bsum1024(t < 256 ? zr * zr : 0.f, red, t);
  if (t == 0) sigma[0] = sqrtf(zz);
}

extern "C" void kernel_launch(void* const* d_in, const int* in_sizes, int n_in,
                              void* d_out, int out_size, void* d_ws, size_t ws_size,
                              hipStream_t stream)
{
  const float* x  = (const float*)d_in[0];
  const float* Wq = (const float*)d_in[1];
  const float* bq = (const float*)d_in[2];
  const float* Wk = (const float*)d_in[3];
  const float* bk = (const float*)d_in[4];
  const float* Wv = (const float*)d_in[5];
  const float* bv = (const float*)d_in[6];
  const float* u0 = (const float*)d_in[7];

  float* out  = (float*)d_out;
  float* out0 = out;             // q-split -> chain scratch -> weighted
  float* out1 = out + BIG;       // k-split -> chain scratch -> attention
  short* out0s = (short*)out0;
  short* out1s = (short*)out1;

  short* qhi = out0s;
  short* qlo = out0s + 32768LL * 256;
  short* khi = out1s;
  short* klo = out1s + 32768LL * 256;

  float* ws         = (float*)d_ws;
  float* scores_buf = ws;          // x-splits during proj; then [B,N,N] fp32 scores
  float* vals_buf   = ws + BIG;    // [B,N,D] RAW x@Wv^T (no sigma, no bias)
  float* partials   = ws + 2 * BIG;   // [12][1024]: 8 norm^2 partials per batch
  float* sigma      = partials + 13 * 1024;
  float* rho_inv    = sigma + 4;      // 128 floats
  short* wsplit     = (short*)(rho_inv + 128);  // [6][MAT] bf16 weight splits

  short* xhi = (short*)scores_buf;            // BIG shorts
  short* xlo = xhi + BIG;

  dim3 blk(256);

  // 0) pre-split weights AND x -> bf16 hi/lo (x-splits dead once proj done)
  split_inputs<<<dim3(4288, 1, 1), blk, 0, stream>>>(Wq, Wk, Wv, wsplit, x, xhi, xlo);

  // 1) projections: q,k split bf16 -> out0/out1; raw vals -> ws
  proj_qkv<<<dim3(1536, 1, 1), blk, 0, stream>>>(
      xhi, xlo, wsplit, bq, bk, qhi, qlo, khi, klo, vals_buf);

  // 2) scores = q @ k^T -> ws (fp32, overwrites x-splits), norm^2 -> slot 0
  scores_st<<<dim3(512, 1, 1), blk, 0, stream>>>(
      qhi, qlo, khi, klo, scores_buf, partials);

  // 3) sigma power iteration
  sigma_kernel<<<1, dim3(1024), 0, stream>>>(Wv, u0, sigma);

  // 4) squaring 1: S (fp32, split) -> bf16 M1 in out0s, norm slot 1
  sq_f32bf<<<dim3(512, 1, 1), blk, 0, stream>>>(scores_buf, out0s, partials, partials + 1024);

  // 5) squarings 2..10: bf16 chain (M2..M10, slots 2..10)
  const short* cin = out0s;
  for (int i = 0; i < 9; i++) {
    short* cout = (i & 1) ? out0s : out1s;
    sq_bf<true><<<dim3(1024, 1, 1), blk, 0, stream>>>(cin, cout,
        partials + (1 + i) * 1024, partials + (2 + i) * 1024);
    cin = cout;
  }
  // 6) squaring 11: norm only (slot 11); term 12 folded into rho_finalize
  sq_bf<false><<<dim3(1024, 1, 1), blk, 0, stream>>>(cin, nullptr,
      partials + 10 * 1024, partials + 11 * 1024);

  // 7) rho_inv finalize (Gelfand log-sum, last term weight x1.5)
  rho_finalize<<<1, dim3(128), 0, stream>>>(partials, rho_inv);

  // 8) final: weighted = (S @ (vals/sigma + bv)) * rho_inv -> out0,
  //    attention = S * rho_inv -> out1 (A-staging). alpha = rho_inv[bz] (smode 2).
  gemm_mfma<false, true><<<dim3(512, 1, 1), blk, 0, stream>>>(
      scores_buf, vals_buf, out0, MAT, MAT, MAT, nullptr, rho_inv, 1, 2, nullptr,
      out1, nullptr, nullptr, nullptr, nullptr, nullptr, sigma, bv);
}

// Round 13
// 460.007 us; speedup vs baseline: 1.0838x; 1.0216x over previous
//
#include <hip/hip_runtime.h>
#include <hip/hip_bf16.h>

// B=128, N=256, D=H=256. out = [weighted (B*N*D), attention (B*N*N)] fp32.
// = Round-12 structure with the Gelfand chain shortened by ONE MORE squaring:
//   terms 11,12 both folded into n10 (weight x1.75 = (2^-11+2^-12+2^-13)/2^-11).
//   Worst-case (complex-pair oscillation) output shift ~2e-3 << tolerance;
//   previous fold (3x smaller bound) showed ZERO absmax shift.
//   Chain: sq_f32bf + 8x sq_bf<true> (-> M9) + sq_bf<false> (n10 only).
// proj_qkv: no prefetch (62-65 µs median). scores_st: prefetch version.
// Final: smode-2 gemm_mfma; rho via rho_finalize (last-term weight x1.75).

#define NB 128
#define MAT 65536
#define BIG 8388608LL

typedef __attribute__((ext_vector_type(4))) float floatx4;
typedef __attribute__((ext_vector_type(4))) float f4v;
typedef __attribute__((ext_vector_type(8))) short short8v;
typedef __attribute__((ext_vector_type(4))) short short4v;

__device__ __forceinline__ short f2bf(float x) {
  union { float f; unsigned u; } v; v.f = x;
  unsigned r = v.u + 0x7fff + ((v.u >> 16) & 1);
  return (short)(r >> 16);
}
__device__ __forceinline__ float bf2f(short h) {
  union { unsigned u; float f; } v; v.u = ((unsigned)(unsigned short)h) << 16; return v.f;
}

// ---------------- generic split-bf16 GEMM (FINAL GEMM only) ------------------------
template<bool TB, bool BATCHED>
__global__ __launch_bounds__(256) void gemm_mfma(
    const float* __restrict__ A, const float* __restrict__ B, float* __restrict__ C,
    long long sA, long long sB, long long sC,
    const float* __restrict__ bias,
    const float* __restrict__ scale_ptr, int sstride, int smode,
    float* __restrict__ norm_out,
    float* __restrict__ att_out,
    const float* __restrict__ B2, const float* __restrict__ bias2, float* __restrict__ C2,
    const float* __restrict__ B3, float* __restrict__ C3,
    const float* __restrict__ bsc, const float* __restrict__ bsb)
{
  __shared__ short sAhi[128 * 32], sAlo[128 * 32];
  __shared__ short sBhi[128 * 40], sBlo[128 * 40];

  int bz, m0, n0;
  if constexpr (BATCHED) {
    int lin = blockIdx.x;
    int xcd = lin & 7;
    int s = lin >> 3;
    bz = xcd * 16 + (s >> 2);
    int tile = s & 3;
    m0 = (tile >> 1) * 128;
    n0 = (tile & 1) * 128;
  } else {
    bz = 0;
    m0 = blockIdx.y * 128;
    n0 = (blockIdx.x & 1) * 128;
    int sel = blockIdx.x >> 1;
    if (sel == 1) { B = B2; bias = bias2; C = C2; }
    else if (sel == 2) { B = B3; bias = nullptr; C = C3; }
  }
  A += (long long)bz * sA;
  B += (long long)bz * sB;
  C += (long long)bz * sC;

  const int t = threadIdx.x;
  const int lane = t & 63;
  const int wave = t >> 6;
  const int wm = wave >> 1, wn = wave & 1;
  const int q = lane >> 4, c16 = lane & 15;

  float alpha = 1.0f;
  if (smode == 1) alpha = 1.0f / scale_ptr[bz * sstride];
  else if (smode == 2) alpha = scale_ptr[bz * sstride];

  float rinv_att = alpha;
  const bool do_att = (att_out != nullptr) && (n0 == 0);

  float binv = 1.0f;
  if (bsc) binv = 1.0f / bsc[0];

  floatx4 acc[4][4];
  #pragma unroll
  for (int i = 0; i < 4; i++)
    #pragma unroll
    for (int j = 0; j < 4; j++)
      acc[i][j] = (floatx4){0.f, 0.f, 0.f, 0.f};

  for (int k0 = 0; k0 < 256; k0 += 32) {
    #pragma unroll
    for (int i = 0; i < 4; i++) {
      int f = t + i * 256;
      int row = f >> 3, c4 = f & 7;
      f4v v = *(const f4v*)(A + (long long)(m0 + row) * 256 + k0 + c4 * 4);
      if (do_att)
        *(f4v*)(att_out + (long long)bz * MAT + (long long)(m0 + row) * 256 + k0 + c4 * 4)
            = v * rinv_att;
      short4v h, l;
      #pragma unroll
      for (int e = 0; e < 4; e++) {
        short hh = f2bf(v[e]);
        h[e] = hh;
        l[e] = f2bf(v[e] - bf2f(hh));
      }
      *(short4v*)&sAhi[row * 32 + c4 * 4] = h;
      *(short4v*)&sAlo[row * 32 + c4 * 4] = l;
    }
    if constexpr (TB) {
      #pragma unroll
      for (int i = 0; i < 4; i++) {
        int f = t + i * 256;
        int row = f >> 3, c4 = f & 7;
        f4v v = *(const f4v*)(B + (long long)(n0 + row) * 256 + k0 + c4 * 4);
        short4v h, l;
        #pragma unroll
        for (int e = 0; e < 4; e++) {
          short hh = f2bf(v[e]);
          h[e] = hh;
          l[e] = f2bf(v[e] - bf2f(hh));
        }
        *(short4v*)&sBhi[row * 40 + c4 * 4] = h;
        *(short4v*)&sBlo[row * 40 + c4 * 4] = l;
      }
      __syncthreads();
    } else {
      __shared__ float sT[32 * 132];
      #pragma unroll
      for (int i = 0; i < 4; i++) {
        int f = t + i * 256;
        int kk = f >> 5, n4 = f & 31;
        f4v v = *(const f4v*)(B + (long long)(k0 + kk) * 256 + n0 + n4 * 4);
        if (bsb) {
          #pragma unroll
          for (int e = 0; e < 4; e++) v[e] = v[e] * binv + bsb[n0 + n4 * 4 + e];
        }
        *(f4v*)&sT[kk * 132 + n4 * 4] = v;
      }
      __syncthreads();
      int n = t & 127, kh = t >> 7;
      short8v h0, h1, l0, l1;
      #pragma unroll
      for (int j = 0; j < 8; j++) {
        float x0 = sT[(kh * 16 + j) * 132 + n];
        float x1 = sT[(kh * 16 + 8 + j) * 132 + n];
        short a0 = f2bf(x0), a1 = f2bf(x1);
        h0[j] = a0; l0[j] = f2bf(x0 - bf2f(a0));
        h1[j] = a1; l1[j] = f2bf(x1 - bf2f(a1));
      }
      *(short8v*)&sBhi[n * 40 + kh * 16] = h0;
      *(short8v*)&sBhi[n * 40 + kh * 16 + 8] = h1;
      *(short8v*)&sBlo[n * 40 + kh * 16] = l0;
      *(short8v*)&sBlo[n * 40 + kh * 16 + 8] = l1;
      __syncthreads();
    }

    short8v ah[4], al[4], bh[4], bl[4];
    #pragma unroll
    for (int fi = 0; fi < 4; fi++) {
      int r = wm * 64 + fi * 16 + c16;
      ah[fi] = *(short8v*)&sAhi[r * 32 + q * 8];
      al[fi] = *(short8v*)&sAlo[r * 32 + q * 8];
    }
    #pragma unroll
    for (int fj = 0; fj < 4; fj++) {
      int r = wn * 64 + fj * 16 + c16;
      bh[fj] = *(short8v*)&sBhi[r * 40 + q * 8];
      bl[fj] = *(short8v*)&sBlo[r * 40 + q * 8];
    }
    #pragma unroll
    for (int fi = 0; fi < 4; fi++)
      #pragma unroll
      for (int fj = 0; fj < 4; fj++) {
        acc[fi][fj] = __builtin_amdgcn_mfma_f32_16x16x32_bf16(al[fi], bh[fj], acc[fi][fj], 0, 0, 0);
        acc[fi][fj] = __builtin_amdgcn_mfma_f32_16x16x32_bf16(ah[fi], bl[fj], acc[fi][fj], 0, 0, 0);
        acc[fi][fj] = __builtin_amdgcn_mfma_f32_16x16x32_bf16(ah[fi], bh[fj], acc[fi][fj], 0, 0, 0);
      }
    __syncthreads();
  }

  float ssq = 0.f;
  #pragma unroll
  for (int fi = 0; fi < 4; fi++) {
    #pragma unroll
    for (int fj = 0; fj < 4; fj++) {
      int col = n0 + wn * 64 + fj * 16 + c16;
      float bb = bias ? bias[col] : 0.f;
      #pragma unroll
      for (int r = 0; r < 4; r++) {
        int row = m0 + wm * 64 + fi * 16 + q * 4 + r;
        float v = acc[fi][fj][r] * alpha + bb;
        C[(long long)row * 256 + col] = v;
        ssq += v * v;
      }
    }
  }

  if (norm_out) {
    float* red = (float*)sAhi;
    red[t] = ssq;
    __syncthreads();
    for (int off = 128; off > 0; off >>= 1) {
      if (t < off) red[t] += red[t + off];
      __syncthreads();
    }
    if (t == 0) {
      int tl = ((m0 >> 7) << 1) | (n0 >> 7);
      norm_out[bz * 4 + tl] = red[0];
    }
  }
}

// ---------------- split inputs: Wq/Wk/Wv and x -> bf16 hi/lo -----------------------
__global__ __launch_bounds__(256) void split_inputs(
    const float* __restrict__ Wq, const float* __restrict__ Wk,
    const float* __restrict__ Wv, short* __restrict__ ws6,
    const float* __restrict__ x, short* __restrict__ xhi, short* __restrict__ xlo)
{
  int b = blockIdx.x;
  int t = threadIdx.x;
  if (b < 192) {
    int gid = b * 256 + t;
    int m = gid >> 14;                          // 0..2
    int off = (gid & 16383) * 4;
    const float* src = (m == 0) ? Wq : (m == 1) ? Wk : Wv;
    f4v v = *(const f4v*)(src + off);
    short4v h, l;
    #pragma unroll
    for (int e = 0; e < 4; e++) {
      short hh = f2bf(v[e]);
      h[e] = hh;
      l[e] = f2bf(v[e] - bf2f(hh));
    }
    *(short4v*)&ws6[(long long)(m * 2) * MAT + off] = h;
    *(short4v*)&ws6[(long long)(m * 2 + 1) * MAT + off] = l;
  } else {
    long long off = ((long long)(b - 192) * 256 + t) * 8;
    #pragma unroll
    for (int half = 0; half < 2; half++) {
      f4v v = *(const f4v*)(x + off + half * 4);
      short4v h, l;
      #pragma unroll
      for (int e = 0; e < 4; e++) {
        short hh = f2bf(v[e]);
        h[e] = hh;
        l[e] = f2bf(v[e] - bf2f(hh));
      }
      *(short4v*)&xhi[off + half * 4] = h;
      *(short4v*)&xlo[off + half * 4] = l;
    }
  }
}

// ---------------- projections: XCD-grouped, copy-staged A AND B (NO prefetch) ------
__global__ __launch_bounds__(256) void proj_qkv(
    const short* __restrict__ xhi, const short* __restrict__ xlo,
    const short* __restrict__ wsp,
    const float* __restrict__ bq, const float* __restrict__ bk,
    short* __restrict__ qhi, short* __restrict__ qlo,
    short* __restrict__ khi, short* __restrict__ klo,
    float* __restrict__ vals)
{
  __shared__ short sAhi[128 * 32], sAlo[128 * 32];
  __shared__ short sBhi[128 * 40], sBlo[128 * 40];

  const int lin = blockIdx.x;
  const int xcd = lin & 7;
  const int idx = lin >> 3;
  const int mloc = idx / 6;
  const int s6 = idx - mloc * 6;
  const int m0 = (xcd * 32 + mloc) * 128;
  const int sel = s6 >> 1;
  const int n0 = (s6 & 1) * 128;

  const short* wb_hi = wsp + (long long)(sel * 2) * MAT;
  const short* wb_lo = wsp + (long long)(sel * 2 + 1) * MAT;

  const int t = threadIdx.x;
  const int lane = t & 63;
  const int wave = t >> 6;
  const int wm = wave >> 1, wn = wave & 1;
  const int q = lane >> 4, c16 = lane & 15;

  floatx4 acc[4][4];
  #pragma unroll
  for (int i = 0; i < 4; i++)
    #pragma unroll
    for (int j = 0; j < 4; j++)
      acc[i][j] = (floatx4){0.f, 0.f, 0.f, 0.f};

  for (int k0 = 0; k0 < 256; k0 += 32) {
    #pragma unroll
    for (int i = 0; i < 2; i++) {
      int chunk = t + i * 256;                 // 0..511
      int row = chunk >> 2, c8 = chunk & 3;
      long long ga = (long long)(m0 + row) * 256 + k0 + c8 * 8;
      *(short8v*)&sAhi[row * 32 + c8 * 8] = *(const short8v*)(xhi + ga);
      *(short8v*)&sAlo[row * 32 + c8 * 8] = *(const short8v*)(xlo + ga);
    }
    #pragma unroll
    for (int i = 0; i < 2; i++) {
      int chunk = t + i * 256;
      int row = chunk >> 2, c8 = chunk & 3;
      long long gr = (long long)(n0 + row) * 256 + k0 + c8 * 8;
      *(short8v*)&sBhi[row * 40 + c8 * 8] = *(const short8v*)(wb_hi + gr);
      *(short8v*)&sBlo[row * 40 + c8 * 8] = *(const short8v*)(wb_lo + gr);
    }
    __syncthreads();

    short8v ah[4], al[4], bh[4], bl[4];
    #pragma unroll
    for (int fi = 0; fi < 4; fi++) {
      int r = wm * 64 + fi * 16 + c16;
      ah[fi] = *(short8v*)&sAhi[r * 32 + q * 8];
      al[fi] = *(short8v*)&sAlo[r * 32 + q * 8];
    }
    #pragma unroll
    for (int fj = 0; fj < 4; fj++) {
      int r = wn * 64 + fj * 16 + c16;
      bh[fj] = *(short8v*)&sBhi[r * 40 + q * 8];
      bl[fj] = *(short8v*)&sBlo[r * 40 + q * 8];
    }
    #pragma unroll
    for (int fi = 0; fi < 4; fi++)
      #pragma unroll
      for (int fj = 0; fj < 4; fj++) {
        acc[fi][fj] = __builtin_amdgcn_mfma_f32_16x16x32_bf16(al[fi], bh[fj], acc[fi][fj], 0, 0, 0);
        acc[fi][fj] = __builtin_amdgcn_mfma_f32_16x16x32_bf16(ah[fi], bl[fj], acc[fi][fj], 0, 0, 0);
        acc[fi][fj] = __builtin_amdgcn_mfma_f32_16x16x32_bf16(ah[fi], bh[fj], acc[fi][fj], 0, 0, 0);
      }
    __syncthreads();
  }

  if (sel < 2) {
    short* ohi = sel ? khi : qhi;
    short* olo = sel ? klo : qlo;
    const float* bb = sel ? bk : bq;
    #pragma unroll
    for (int fi = 0; fi < 4; fi++)
      #pragma unroll
      for (int fj = 0; fj < 4; fj++) {
        int col = n0 + wn * 64 + fj * 16 + c16;
        float b = bb[col];
        #pragma unroll
        for (int r = 0; r < 4; r++) {
          long long row = m0 + wm * 64 + fi * 16 + q * 4 + r;
          float v = acc[fi][fj][r] + b;
          short h = f2bf(v);
          ohi[row * 256 + col] = h;
          olo[row * 256 + col] = f2bf(v - bf2f(h));
        }
      }
  } else {
    #pragma unroll
    for (int fi = 0; fi < 4; fi++)
      #pragma unroll
      for (int fj = 0; fj < 4; fj++) {
        int col = n0 + wn * 64 + fj * 16 + c16;
        #pragma unroll
        for (int r = 0; r < 4; r++) {
          long long row = m0 + wm * 64 + fi * 16 + q * 4 + r;
          vals[row * 256 + col] = acc[fi][fj][r];
        }
      }
  }
}

// ---------------- scores = q @ k^T: copy-staged + register prefetch ----------------
// norm slot 8-wide: writes bz*8+tile, zeros 4..7.
__global__ __launch_bounds__(256) void scores_st(
    const short* __restrict__ qhi, const short* __restrict__ qlo,
    const short* __restrict__ khi, const short* __restrict__ klo,
    float* __restrict__ S, float* __restrict__ norm_out)
{
  __shared__ short sAhi[128 * 32], sAlo[128 * 32];
  __shared__ short sBhi[128 * 40], sBlo[128 * 40];
  __shared__ float red[256];

  const int lin = blockIdx.x;
  const int xcd = lin & 7, s = lin >> 3;
  const int bz = xcd * 16 + (s >> 2);
  const int tile = s & 3;
  const int m0 = (tile >> 1) * 128, n0 = (tile & 1) * 128;

  const int t = threadIdx.x;
  const int lane = t & 63;
  const int wave = t >> 6;
  const int wm = wave >> 1, wn = wave & 1;
  const int q = lane >> 4, c16 = lane & 15;
  const int srow = t >> 2, sc8 = (t & 3) * 8;

  floatx4 acc[4][4];
  #pragma unroll
  for (int i = 0; i < 4; i++)
    #pragma unroll
    for (int j = 0; j < 4; j++)
      acc[i][j] = (floatx4){0.f, 0.f, 0.f, 0.f};

  const long long abase = (long long)(bz * 256 + m0) * 256;
  const long long bbase = (long long)(bz * 256 + n0) * 256;

  short8v pAh[2], pAl[2], pBh[2], pBl[2];
  {
    #pragma unroll
    for (int i = 0; i < 2; i++) {
      long long ga = abase + (long long)(srow + i * 64) * 256 + sc8;
      long long gb = bbase + (long long)(srow + i * 64) * 256 + sc8;
      pAh[i] = *(const short8v*)(qhi + ga);
      pAl[i] = *(const short8v*)(qlo + ga);
      pBh[i] = *(const short8v*)(khi + gb);
      pBl[i] = *(const short8v*)(klo + gb);
    }
  }

  for (int k0 = 0; k0 < 256; k0 += 32) {
    #pragma unroll
    for (int i = 0; i < 2; i++) {
      int row = srow + i * 64;
      *(short8v*)&sAhi[row * 32 + sc8] = pAh[i];
      *(short8v*)&sAlo[row * 32 + sc8] = pAl[i];
      *(short8v*)&sBhi[row * 40 + sc8] = pBh[i];
      *(short8v*)&sBlo[row * 40 + sc8] = pBl[i];
    }
    __syncthreads();

    if (k0 < 224) {
      int kn = k0 + 32;
      #pragma unroll
      for (int i = 0; i < 2; i++) {
        long long ga = abase + (long long)(srow + i * 64) * 256 + kn + sc8;
        long long gb = bbase + (long long)(srow + i * 64) * 256 + kn + sc8;
        pAh[i] = *(const short8v*)(qhi + ga);
        pAl[i] = *(const short8v*)(qlo + ga);
        pBh[i] = *(const short8v*)(khi + gb);
        pBl[i] = *(const short8v*)(klo + gb);
      }
    }

    short8v ah[4], al[4], bh[4], bl[4];
    #pragma unroll
    for (int fi = 0; fi < 4; fi++) {
      int r = wm * 64 + fi * 16 + c16;
      ah[fi] = *(short8v*)&sAhi[r * 32 + q * 8];
      al[fi] = *(short8v*)&sAlo[r * 32 + q * 8];
    }
    #pragma unroll
    for (int fj = 0; fj < 4; fj++) {
      int r = wn * 64 + fj * 16 + c16;
      bh[fj] = *(short8v*)&sBhi[r * 40 + q * 8];
      bl[fj] = *(short8v*)&sBlo[r * 40 + q * 8];
    }
    #pragma unroll
    for (int fi = 0; fi < 4; fi++)
      #pragma unroll
      for (int fj = 0; fj < 4; fj++) {
        acc[fi][fj] = __builtin_amdgcn_mfma_f32_16x16x32_bf16(al[fi], bh[fj], acc[fi][fj], 0, 0, 0);
        acc[fi][fj] = __builtin_amdgcn_mfma_f32_16x16x32_bf16(ah[fi], bl[fj], acc[fi][fj], 0, 0, 0);
        acc[fi][fj] = __builtin_amdgcn_mfma_f32_16x16x32_bf16(ah[fi], bh[fj], acc[fi][fj], 0, 0, 0);
      }
    __syncthreads();
  }

  float* C = S + (long long)bz * MAT;
  float ssq = 0.f;
  #pragma unroll
  for (int fi = 0; fi < 4; fi++)
    #pragma unroll
    for (int fj = 0; fj < 4; fj++) {
      int col = n0 + wn * 64 + fj * 16 + c16;
      #pragma unroll
      for (int r = 0; r < 4; r++) {
        int row = m0 + wm * 64 + fi * 16 + q * 4 + r;
        float v = acc[fi][fj][r];
        C[(long long)row * 256 + col] = v;
        ssq += v * v;
      }
    }

  red[t] = ssq;
  __syncthreads();
  for (int o = 128; o > 0; o >>= 1) {
    if (t < o) red[t] += red[t + o];
    __syncthreads();
  }
  if (t == 0) norm_out[bz * 8 + tile] = red[0];
  if (t == 1) norm_out[bz * 8 + 4 + tile] = 0.f;
}

// ---------------- chain epilogue (sq_f32bf): alpha*acc -> bf16 tile + norm ---------
__device__ __forceinline__ void chain_epilogue(
    short* LB, float* red, floatx4 (&acc)[4][4], float alpha,
    int m0, int n0, int wm, int wn, int q, int c16, int t,
    short* __restrict__ Mout,
    float* __restrict__ nout, int nidx, bool write_out)
{
  __syncthreads();
  float ssq = 0.f;
  #pragma unroll
  for (int fi = 0; fi < 4; fi++)
    #pragma unroll
    for (int fj = 0; fj < 4; fj++) {
      int lcol = wn * 64 + fj * 16 + c16;
      #pragma unroll
      for (int r = 0; r < 4; r++) {
        int lrow = wm * 64 + fi * 16 + q * 4 + r;
        float v = acc[fi][fj][r] * alpha;
        ssq += v * v;
        if (write_out) LB[lrow * 128 + lcol] = f2bf(v);
      }
    }

  if (write_out) {
    __syncthreads();
    int lr = t >> 1, off = (t & 1) * 64;
    #pragma unroll
    for (int jc = 0; jc < 8; jc++)
      *(short8v*)(Mout + (long long)(m0 + lr) * 256 + n0 + off + jc * 8)
          = *(const short8v*)&LB[lr * 128 + off + jc * 8];
  }

  red[t] = ssq;
  __syncthreads();
  for (int off2 = 128; off2 > 0; off2 >>= 1) {
    if (t < off2) red[t] += red[t + off2];
    __syncthreads();
  }
  if (t == 0) nout[nidx] = red[0];
}

// ---------------- squaring 1: fp32 S (split 3-MFMA) -> bf16 M ----------------------
// norm slot 8-wide (writes bz*8+tile, zeros 4..7).
__global__ __launch_bounds__(256) void sq_f32bf(
    const float* __restrict__ S, short* __restrict__ Mo,
    const float* __restrict__ nprev, float* __restrict__ nout)
{
  __shared__ short SM[18432];
  __shared__ float sT[32 * 132];
  __shared__ float red[256];
  short* sAhi = SM;
  short* sAlo = SM + 4096;
  short* sBhi = SM + 8192;
  short* sBlo = SM + 13312;

  int lin = blockIdx.x;
  int xcd = lin & 7, s = lin >> 3;
  int bz = xcd * 16 + (s >> 2);
  int tile = s & 3;
  int m0 = (tile >> 1) * 128, n0 = (tile & 1) * 128;
  const float* A = S + (long long)bz * MAT;

  const int t = threadIdx.x;
  const int lane = t & 63;
  const int wave = t >> 6;
  const int wm = wave >> 1, wn = wave & 1;
  const int q = lane >> 4, c16 = lane & 15;

  floatx4 acc[4][4];
  #pragma unroll
  for (int i = 0; i < 4; i++)
    #pragma unroll
    for (int j = 0; j < 4; j++)
      acc[i][j] = (floatx4){0.f, 0.f, 0.f, 0.f};

  for (int k0 = 0; k0 < 256; k0 += 32) {
    #pragma unroll
    for (int i = 0; i < 4; i++) {
      int f = t + i * 256;
      int row = f >> 3, c4 = f & 7;
      f4v v = *(const f4v*)(A + (long long)(m0 + row) * 256 + k0 + c4 * 4);
      short4v h, l;
      #pragma unroll
      for (int e = 0; e < 4; e++) {
        short hh = f2bf(v[e]);
        h[e] = hh;
        l[e] = f2bf(v[e] - bf2f(hh));
      }
      *(short4v*)&sAhi[row * 32 + c4 * 4] = h;
      *(short4v*)&sAlo[row * 32 + c4 * 4] = l;
    }
    #pragma unroll
    for (int i = 0; i < 4; i++) {
      int f = t + i * 256;
      int kk = f >> 5, n4 = f & 31;
      f4v v = *(const f4v*)(A + (long long)(k0 + kk) * 256 + n0 + n4 * 4);
      *(f4v*)&sT[kk * 132 + n4 * 4] = v;
    }
    __syncthreads();
    {
      int n = t & 127, kh = t >> 7;
      short8v h0, h1, l0, l1;
      #pragma unroll
      for (int j = 0; j < 8; j++) {
        float x0 = sT[(kh * 16 + j) * 132 + n];
        float x1 = sT[(kh * 16 + 8 + j) * 132 + n];
        short a0 = f2bf(x0), a1 = f2bf(x1);
        h0[j] = a0; l0[j] = f2bf(x0 - bf2f(a0));
        h1[j] = a1; l1[j] = f2bf(x1 - bf2f(a1));
      }
      *(short8v*)&sBhi[n * 40 + kh * 16] = h0;
      *(short8v*)&sBhi[n * 40 + kh * 16 + 8] = h1;
      *(short8v*)&sBlo[n * 40 + kh * 16] = l0;
      *(short8v*)&sBlo[n * 40 + kh * 16 + 8] = l1;
    }
    __syncthreads();

    short8v ah[4], al[4], bh[4], bl[4];
    #pragma unroll
    for (int fi = 0; fi < 4; fi++) {
      int r = wm * 64 + fi * 16 + c16;
      ah[fi] = *(short8v*)&sAhi[r * 32 + q * 8];
      al[fi] = *(short8v*)&sAlo[r * 32 + q * 8];
    }
    #pragma unroll
    for (int fj = 0; fj < 4; fj++) {
      int r = wn * 64 + fj * 16 + c16;
      bh[fj] = *(short8v*)&sBhi[r * 40 + q * 8];
      bl[fj] = *(short8v*)&sBlo[r * 40 + q * 8];
    }
    #pragma unroll
    for (int fi = 0; fi < 4; fi++)
      #pragma unroll
      for (int fj = 0; fj < 4; fj++) {
        acc[fi][fj] = __builtin_amdgcn_mfma_f32_16x16x32_bf16(al[fi], bh[fj], acc[fi][fj], 0, 0, 0);
        acc[fi][fj] = __builtin_amdgcn_mfma_f32_16x16x32_bf16(ah[fi], bl[fj], acc[fi][fj], 0, 0, 0);
        acc[fi][fj] = __builtin_amdgcn_mfma_f32_16x16x32_bf16(ah[fi], bh[fj], acc[fi][fj], 0, 0, 0);
      }
    __syncthreads();
  }

  const float* p = nprev + bz * 8;
  float alpha = 1.0f / (p[0] + p[1] + p[2] + p[3]);
  chain_epilogue(SM, red, acc, alpha, m0, n0, wm, wn, q, c16, t,
                 Mo + (long long)bz * MAT, nout, bz * 8 + tile, true);
  if (t == 1) nout[bz * 8 + 4 + tile] = 0.f;
}

// ---------------- squarings 2..: 1024 blocks, 64x128 tiles, dbuf + prefetch --------
template<bool WRITE_OUT>
__global__ __launch_bounds__(256) void sq_bf(
    const short* __restrict__ Mi, short* __restrict__ Mo,
    const float* __restrict__ nprev, float* __restrict__ nout)
{
  __shared__ short SMEM[9216];    // Bs dbuf = 2 x [128][36]; epilogue LB 64x128 fits
  __shared__ float red[4];
  short* BsA = SMEM;
  short* BsB = SMEM + 4608;

  int lin = blockIdx.x;
  int xcd = lin & 7, s = lin >> 3;     // s 0..127
  int bz = xcd * 16 + (s >> 3);
  int tile = s & 7;
  int m0 = (tile >> 1) * 64, n0 = (tile & 1) * 128;

  const short* A = Mi + (long long)bz * MAT;

  const int t = threadIdx.x;
  const int lane = t & 63;
  const int wave = t >> 6;
  const int wm = wave >> 1, wn = wave & 1;   // wave tile 32x64
  const int q = lane >> 4, c16 = lane & 15;
  const int g = t >> 5, cc = t & 31;   // staging: 8 k-groups x 32 col-chunks

  floatx4 acc[2][4];
  #pragma unroll
  for (int i = 0; i < 2; i++)
    #pragma unroll
    for (int j = 0; j < 4; j++)
      acc[i][j] = (floatx4){0.f, 0.f, 0.f, 0.f};

  short4v r0 = *(const short4v*)(A + (long long)(g * 4 + 0) * 256 + n0 + cc * 4);
  short4v r1 = *(const short4v*)(A + (long long)(g * 4 + 1) * 256 + n0 + cc * 4);
  short4v r2 = *(const short4v*)(A + (long long)(g * 4 + 2) * 256 + n0 + cc * 4);
  short4v r3 = *(const short4v*)(A + (long long)(g * 4 + 3) * 256 + n0 + cc * 4);

  for (int k0 = 0; k0 < 256; k0 += 32) {
    short* Bw = ((k0 >> 5) & 1) ? BsB : BsA;
    #pragma unroll
    for (int j = 0; j < 4; j++) {
      short4v w4 = (short4v){r0[j], r1[j], r2[j], r3[j]};
      *(short4v*)&Bw[(cc * 4 + j) * 36 + g * 4] = w4;
    }
    __syncthreads();

    if (k0 < 224) {
      int kn = k0 + 32;
      r0 = *(const short4v*)(A + (long long)(kn + g * 4 + 0) * 256 + n0 + cc * 4);
      r1 = *(const short4v*)(A + (long long)(kn + g * 4 + 1) * 256 + n0 + cc * 4);
      r2 = *(const short4v*)(A + (long long)(kn + g * 4 + 2) * 256 + n0 + cc * 4);
      r3 = *(const short4v*)(A + (long long)(kn + g * 4 + 3) * 256 + n0 + cc * 4);
    }

    short8v a[2], b[4];
    #pragma unroll
    for (int fi = 0; fi < 2; fi++)
      a[fi] = *(const short8v*)(A + (long long)(m0 + wm * 32 + fi * 16 + c16) * 256 + k0 + q * 8);
    #pragma unroll
    for (int fj = 0; fj < 4; fj++) {
      int n = wn * 64 + fj * 16 + c16;
      short4v lo = *(const short4v*)&Bw[n * 36 + q * 8];
      short4v hi = *(const short4v*)&Bw[n * 36 + q * 8 + 4];
      b[fj] = __builtin_shufflevector(lo, hi, 0, 1, 2, 3, 4, 5, 6, 7);
    }
    #pragma unroll
    for (int fi = 0; fi < 2; fi++)
      #pragma unroll
      for (int fj = 0; fj < 4; fj++)
        acc[fi][fj] = __builtin_amdgcn_mfma_f32_16x16x32_bf16(a[fi], b[fj], acc[fi][fj], 0, 0, 0);
  }

  const float* p = nprev + bz * 8;
  float alpha = 1.0f / (p[0] + p[1] + p[2] + p[3] + p[4] + p[5] + p[6] + p[7]);

  __syncthreads();   // all Bw reads of the k-loop consumed before LB reuse
  short* LB = SMEM;
  float ssq = 0.f;
  #pragma unroll
  for (int fi = 0; fi < 2; fi++)
    #pragma unroll
    for (int fj = 0; fj < 4; fj++) {
      int lcol = wn * 64 + fj * 16 + c16;
      #pragma unroll
      for (int r = 0; r < 4; r++) {
        int lrow = wm * 32 + fi * 16 + q * 4 + r;
        float v = acc[fi][fj][r] * alpha;
        ssq += v * v;
        if (WRITE_OUT) LB[lrow * 128 + lcol] = f2bf(v);
      }
    }

  if (WRITE_OUT) {
    __syncthreads();
    int lr = t >> 2, off = (t & 3) * 32;
    #pragma unroll
    for (int jc = 0; jc < 4; jc++)
      *(short8v*)(Mo + (long long)bz * MAT + (long long)(m0 + lr) * 256 + n0 + off + jc * 8)
          = *(const short8v*)&LB[lr * 128 + off + jc * 8];
  }

  #pragma unroll
  for (int off2 = 32; off2 > 0; off2 >>= 1)
    ssq += __shfl_xor(ssq, off2, 64);
  if (lane == 0) red[wave] = ssq;
  __syncthreads();
  if (t == 0) nout[bz * 8 + tile] = red[0] + red[1] + red[2] + red[3];
}

// ---------------- rho_inv finalize: Gelfand log-sum over 11 norm slots -------------
// Terms 11,12 folded into term 10 (log n11 ~= log n12 ~= log n10 at convergence):
// weight x1.75 = (2^-11 + 2^-12 + 2^-13) / 2^-11.
__global__ __launch_bounds__(128) void rho_finalize(
    const float* __restrict__ partials, float* __restrict__ rho_inv)
{
  int bz = threadIdx.x;
  float a2 = 0.f, w = 1.0f;
  #pragma unroll
  for (int i2 = 0; i2 <= 10; i2++) {
    const float* p = partials + i2 * 1024 + bz * 8;
    float nm = p[0] + p[1] + p[2] + p[3] + p[4] + p[5] + p[6] + p[7];
    float term = w * 0.5f * logf(nm);
    a2 += (i2 == 10) ? term * 1.75f : term;
    w *= 0.5f;
  }
  rho_inv[bz] = expf(-a2);
}

// ---------------- sigma: 1024-thread power iteration, LDS-cached bf16 W ------------
__device__ __forceinline__ float bsum1024(float x, float* red, int t)
{
  red[t] = x; __syncthreads();
  for (int off = 512; off > 0; off >>= 1) {
    if (t < off) red[t] += red[t + off];
    __syncthreads();
  }
  float r = red[0];
  __syncthreads();
  return r;
}

__global__ __launch_bounds__(1024) void sigma_kernel(
    const float* __restrict__ W, const float* __restrict__ u0, float* __restrict__ sigma)
{
  __shared__ short Wl[65536];
  __shared__ float u[256], v[256], red[1024];
  int t = threadIdx.x;
  int r = t & 255, seg = t >> 8;
  const float eps = 1e-12f;

  #pragma unroll
  for (int i = 0; i < 16; i++) {
    int idx = (i * 1024 + t) * 4;
    f4v w = *(const f4v*)(W + idx);
    short4v h;
    #pragma unroll
    for (int e = 0; e < 4; e++) h[e] = f2bf(w[e]);
    *(short4v*)&Wl[idx] = h;
  }

  float x = (t < 256) ? u0[t] : 0.f;
  float nrm = sqrtf(bsum1024(x * x, red, t));
  if (t < 256) u[t] = x / (nrm + eps);
  __syncthreads();

  for (int it = 0; it < 5; it++) {
    float sv = 0.f;
    #pragma unroll 8
    for (int j = 0; j < 64; j++) {
      int h = seg * 64 + j;
      sv = fmaf(bf2f(Wl[h * 256 + r]), u[h], sv);
    }
    red[t] = sv; __syncthreads();
    float vr = 0.f;
    if (t < 256) vr = red[t] + red[256 + t] + red[512 + t] + red[768 + t];
    __syncthreads();
    nrm = sqrtf(bsum1024(t < 256 ? vr * vr : 0.f, red, t));
    if (t < 256) v[t] = vr / (nrm + eps);
    __syncthreads();
    if (it < 4) {
      float su = 0.f;
      #pragma unroll
      for (int j = 0; j < 16; j++) {
        short4v w4 = *(const short4v*)&Wl[r * 256 + seg * 64 + j * 4];
        const float* vv = &v[seg * 64 + j * 4];
        su += bf2f(w4[0]) * vv[0] + bf2f(w4[1]) * vv[1]
            + bf2f(w4[2]) * vv[2] + bf2f(w4[3]) * vv[3];
      }
      red[t] = su; __syncthreads();
      float ur = 0.f;
      if (t < 256) ur = red[t] + red[256 + t] + red[512 + t] + red[768 + t];
      __syncthreads();
      nrm = sqrtf(bsum1024(t < 256 ? ur * ur : 0.f, red, t));
      if (t < 256) u[t] = ur / (nrm + eps);
      __syncthreads();
    }
  }

  float z = 0.f;
  #pragma unroll
  for (int j = 0; j < 16; j++) {
    f4v w = *(const f4v*)(W + r * 256 + seg * 64 + j * 4);
    const float* vv = &v[seg * 64 + j * 4];
    z += w[0] * vv[0] + w[1] * vv[1] + w[2] * vv[2] + w[3] * vv[3];
  }
  red[t] = z; __syncthreads();
  float zr = 0.f;
  if (t < 256) zr = red[t] + red[256 + t] + red[512 + t] + red[768 + t];
  __syncthreads();
  float zz = bsum1024(t < 256 ? zr * zr : 0.f, red, t);
  if (t == 0) sigma[0] = sqrtf(zz);
}

extern "C" void kernel_launch(void* const* d_in, const int* in_sizes, int n_in,
                              void* d_out, int out_size, void* d_ws, size_t ws_size,
                              hipStream_t stream)
{
  const float* x  = (const float*)d_in[0];
  const float* Wq = (const float*)d_in[1];
  const float* bq = (const float*)d_in[2];
  const float* Wk = (const float*)d_in[3];
  const float* bk = (const float*)d_in[4];
  const float* Wv = (const float*)d_in[5];
  const float* bv = (const float*)d_in[6];
  const float* u0 = (const float*)d_in[7];

  float* out  = (float*)d_out;
  float* out0 = out;             // q-split -> chain scratch -> weighted
  float* out1 = out + BIG;       // k-split -> chain scratch -> attention
  short* out0s = (short*)out0;
  short* out1s = (short*)out1;

  short* qhi = out0s;
  short* qlo = out0s + 32768LL * 256;
  short* khi = out1s;
  short* klo = out1s + 32768LL * 256;

  float* ws         = (float*)d_ws;
  float* scores_buf = ws;          // x-splits during proj; then [B,N,N] fp32 scores
  float* vals_buf   = ws + BIG;    // [B,N,D] RAW x@Wv^T (no sigma, no bias)
  float* partials   = ws + 2 * BIG;   // [11][1024]: 8 norm^2 partials per batch
  float* sigma      = partials + 13 * 1024;
  float* rho_inv    = sigma + 4;      // 128 floats
  short* wsplit     = (short*)(rho_inv + 128);  // [6][MAT] bf16 weight splits

  short* xhi = (short*)scores_buf;            // BIG shorts
  short* xlo = xhi + BIG;

  dim3 blk(256);

  // 0) pre-split weights AND x -> bf16 hi/lo (x-splits dead once proj done)
  split_inputs<<<dim3(4288, 1, 1), blk, 0, stream>>>(Wq, Wk, Wv, wsplit, x, xhi, xlo);

  // 1) projections: q,k split bf16 -> out0/out1; raw vals -> ws
  proj_qkv<<<dim3(1536, 1, 1), blk, 0, stream>>>(
      xhi, xlo, wsplit, bq, bk, qhi, qlo, khi, klo, vals_buf);

  // 2) scores = q @ k^T -> ws (fp32, overwrites x-splits), norm^2 -> slot 0
  scores_st<<<dim3(512, 1, 1), blk, 0, stream>>>(
      qhi, qlo, khi, klo, scores_buf, partials);

  // 3) sigma power iteration
  sigma_kernel<<<1, dim3(1024), 0, stream>>>(Wv, u0, sigma);

  // 4) squaring 1: S (fp32, split) -> bf16 M1 in out0s, norm slot 1
  sq_f32bf<<<dim3(512, 1, 1), blk, 0, stream>>>(scores_buf, out0s, partials, partials + 1024);

  // 5) squarings 2..9: bf16 chain (M2..M9, slots 2..9)
  const short* cin = out0s;
  for (int i = 0; i < 8; i++) {
    short* cout = (i & 1) ? out0s : out1s;
    sq_bf<true><<<dim3(1024, 1, 1), blk, 0, stream>>>(cin, cout,
        partials + (1 + i) * 1024, partials + (2 + i) * 1024);
    cin = cout;
  }
  // 6) squaring 10: norm only (slot 10); terms 11,12 folded into rho_finalize
  sq_bf<false><<<dim3(1024, 1, 1), blk, 0, stream>>>(cin, nullptr,
      partials + 9 * 1024, partials + 10 * 1024);

  // 7) rho_inv finalize (Gelfand log-sum, last term weight x1.75)
  rho_finalize<<<1, dim3(128), 0, stream>>>(partials, rho_inv);

  // 8) final: weighted = (S @ (vals/sigma + bv)) * rho_inv -> out0,
  //    attention = S * rho_inv -> out1 (A-staging). alpha = rho_inv[bz] (smode 2).
  gemm_mfma<false, true><<<dim3(512, 1, 1), blk, 0, stream>>>(
      scores_buf, vals_buf, out0, MAT, MAT, MAT, nullptr, rho_inv, 1, 2, nullptr,
      out1, nullptr, nullptr, nullptr, nullptr, nullptr, sigma, bv);
}